// Round 7
// baseline (4757.721 us; speedup 1.0000x reference)
//
#include <hip/hip_runtime.h>
#include <math.h>

// ---------------------------------------------------------------------------
// DiacritizerD3: split-bf16 MFMA pipeline. Decoder = R3-config persistent
// kernel (LDS weights, batched sc1 h-exchange) FUSED with the next chunk's
// dec_Wx GEMM on the other 128 CUs. R7: GEMM half rebuilt as double-buffered
// single-barrier K-loop (R6 showed it was the critical path at the 1-block/CU
// no-TLP scaling limit: 4x86=344 predicted, 333 measured).
// B=32, TS=16, TW=16, SENT_H=256 (DIN=512), WORD_H=512 (DQ=DEC_H=1024),
// CDIM=32, WDIM=300, DEC_IN=1544.
// ---------------------------------------------------------------------------

typedef __attribute__((ext_vector_type(8))) __bf16 bf16x8;
typedef __attribute__((ext_vector_type(4))) float f32x4;
typedef __attribute__((ext_vector_type(4))) unsigned u32x4;

__device__ __forceinline__ float sigf(float x) { return 1.0f / (1.0f + expf(-x)); }

__device__ __forceinline__ unsigned short bf16rn(float x) {
  unsigned u = __float_as_uint(x);
  return (unsigned short)((u + 0x7fffu + ((u >> 16) & 1u)) >> 16);
}
__device__ __forceinline__ void splitf(float x, unsigned short& h, unsigned short& l) {
  h = bf16rn(x);
  float fh = __uint_as_float((unsigned)h << 16);
  l = bf16rn(x - fh);
}

// cache-bypassing (L1+L2) 16B load via volatile asm: loads issue back-to-back
// and stay in flight; caller pays one s_waitcnt vmcnt(0).
__device__ __forceinline__ void ldg16_cc(u32x4& d, const void* p) {
  asm volatile("global_load_dwordx4 %0, %1, off sc0 sc1" : "=v"(d) : "v"(p));
}

#define FMA16(a, b, acc)                                                           \
  acc[0][0] += a.x * b.x; acc[0][1] += a.x * b.y; acc[0][2] += a.x * b.z; acc[0][3] += a.x * b.w; \
  acc[1][0] += a.y * b.x; acc[1][1] += a.y * b.y; acc[1][2] += a.y * b.z; acc[1][3] += a.y * b.w; \
  acc[2][0] += a.z * b.x; acc[2][1] += a.z * b.y; acc[2][2] += a.z * b.z; acc[2][3] += a.z * b.w; \
  acc[3][0] += a.w * b.x; acc[3][1] += a.w * b.y; acc[3][2] += a.w * b.z; acc[3][3] += a.w * b.w;

// ---------------- transpose ----------------
__global__ __launch_bounds__(256) void transpose_k(const float* __restrict__ in,
                                                   float* __restrict__ out,
                                                   int R, int C, int H) {
  __shared__ float tile[32][33];
  int r0 = blockIdx.x * 32, c0 = blockIdx.y * 32;
  int tx = threadIdx.x & 31, ty = threadIdx.x >> 5;
  for (int yy = ty; yy < 32; yy += 8) {
    int r = r0 + yy, c = c0 + tx;
    float v = 0.f;
    if (r < R && c < C) {
      int gs = H ? ((r & 3) * H + (r >> 2)) : r;
      v = in[(long)gs * C + c];
    }
    tile[yy][tx] = v;
  }
  __syncthreads();
  for (int yy = ty; yy < 32; yy += 8) {
    int c = c0 + yy, r = r0 + tx;
    if (r < R && c < C) out[(long)c * R + r] = tile[tx][yy];
  }
}

// ---------------- embedding lookup ----------------
__global__ void embed_k(const int* __restrict__ sents, const float* __restrict__ word_embs,
                        float* __restrict__ wembs) {
  int idx = blockIdx.x * 256 + threadIdx.x;
  if (idx >= 512 * 300) return;
  int r = idx / 300, k = idx - r * 300;
  wembs[idx] = word_embs[(long)sents[r] * 300 + k];
}

// ---------------- char-encoder input build (writes bf16 hi/lo pairs) --------
__global__ void charin_k(const int* __restrict__ words, const float* __restrict__ char_table,
                         const float* __restrict__ sent_enc,
                         unsigned short* __restrict__ ciH, unsigned short* __restrict__ ciL) {
  int idx = blockIdx.x * 256 + threadIdx.x;
  if (idx >= 512 * 16 * 544) return;
  int k = idx % 544;
  int rc = idx / 544;
  int c = rc & 15, n = rc >> 4;
  int w = words[n * 16 + c];
  float v;
  if (k < 32) v = char_table[w * 32 + k];
  else v = (w != 0) ? sent_enc[n * 512 + (k - 32)] : 0.f;
  unsigned short h, l;
  splitf(v, h, l);
  ciH[idx] = h; ciL[idx] = l;
}

// ---------------- labels -> final[:,1536:1544] (pairs) ----------------------
__global__ void labels_k(const int* __restrict__ labels,
                         unsigned short* __restrict__ fH, unsigned short* __restrict__ fL) {
  int idx = blockIdx.x * 256 + threadIdx.x;
  if (idx >= 8192 * 8) return;
  int r = idx >> 3, l = idx & 7;
  long o = (long)r * 1544 + 1536 + l;
  fH[o] = bf16rn((float)labels[idx]);
  fL[o] = 0;
}

// ---------------- dec_Wh -> fragment-contiguous split layout ----------------
// WhF[nt][kt][lane][8]: col = nt*16+(lane&15) (unit-major), k = kt*32+((lane>>4)&3)*8+j
__global__ void decwh_prep_k(const float* __restrict__ dec_Wh,
                             unsigned short* __restrict__ WhFH,
                             unsigned short* __restrict__ WhFL) {
  long o = (long)blockIdx.x * 256 + threadIdx.x;
  if (o >= 4194304) return;
  int j = (int)(o & 7);
  int lane = (int)((o >> 3) & 63);
  int kt = (int)((o >> 9) & 31);
  int nt = (int)(o >> 14);
  int col = nt * 16 + (lane & 15);
  int gsrc = (col & 3) * 1024 + (col >> 2);
  int k = kt * 32 + ((lane >> 4) & 3) * 8 + j;
  float v = dec_Wh[(long)gsrc * 1024 + k];
  unsigned short h, l;
  splitf(v, h, l);
  WhFH[o] = h; WhFL[o] = l;
}

// ---------------- fp32 fallback GEMM (sentence Wx, classifier) --------------
template <int HASBIAS>
__global__ __launch_bounds__(256) void gemm_k(const float* __restrict__ A, int lda,
                                              const float* __restrict__ Bw,
                                              const float* __restrict__ bias,
                                              float* __restrict__ C, int ldc,
                                              int M, int N, int K) {
  __shared__ float As[32][64];
  __shared__ float Bs[32][64];
  int tid = threadIdx.x;
  int m0 = blockIdx.x * 64, n0 = blockIdx.y * 64;
  int tn = tid & 15, tm = tid >> 4;
  int lrow = tid >> 2, lk = (tid & 3) * 8;
  float acc[4][4] = {};
  int am = m0 + lrow;
  const float* aptr = A + (long)am * lda;
  bool mok = am < M;
  int bn = n0 + lrow;
  const float* bptr = Bw + (long)bn * K;
  bool nok = bn < N;

  for (int k0 = 0; k0 < K; k0 += 32) {
    int kb = k0 + lk;
    if (kb + 8 <= K) {
      if (mok) {
        float4 v0 = *(const float4*)(aptr + kb);
        float4 v1 = *(const float4*)(aptr + kb + 4);
        As[lk + 0][lrow] = v0.x; As[lk + 1][lrow] = v0.y; As[lk + 2][lrow] = v0.z; As[lk + 3][lrow] = v0.w;
        As[lk + 4][lrow] = v1.x; As[lk + 5][lrow] = v1.y; As[lk + 6][lrow] = v1.z; As[lk + 7][lrow] = v1.w;
      } else {
#pragma unroll
        for (int i = 0; i < 8; i++) As[lk + i][lrow] = 0.f;
      }
      if (nok) {
        float4 v0 = *(const float4*)(bptr + kb);
        float4 v1 = *(const float4*)(bptr + kb + 4);
        Bs[lk + 0][lrow] = v0.x; Bs[lk + 1][lrow] = v0.y; Bs[lk + 2][lrow] = v0.z; Bs[lk + 3][lrow] = v0.w;
        Bs[lk + 4][lrow] = v1.x; Bs[lk + 5][lrow] = v1.y; Bs[lk + 6][lrow] = v1.z; Bs[lk + 7][lrow] = v1.w;
      } else {
#pragma unroll
        for (int i = 0; i < 8; i++) Bs[lk + i][lrow] = 0.f;
      }
    } else {
#pragma unroll
      for (int i = 0; i < 8; i++) {
        int k = kb + i;
        As[lk + i][lrow] = (mok && k < K) ? aptr[k] : 0.f;
        Bs[lk + i][lrow] = (nok && k < K) ? bptr[k] : 0.f;
      }
    }
    __syncthreads();
#pragma unroll
    for (int kk = 0; kk < 32; kk++) {
      float4 a = *(const float4*)&As[kk][tm * 4];
      float4 b = *(const float4*)&Bs[kk][tn * 4];
      FMA16(a, b, acc)
    }
    __syncthreads();
  }
#pragma unroll
  for (int i = 0; i < 4; i++) {
    int m = m0 + tm * 4 + i;
    if (m >= M) continue;
#pragma unroll
    for (int j = 0; j < 4; j++) {
      int n = n0 + tn * 4 + j;
      if (n >= N) continue;
      float v = acc[i][j];
      if (HASBIAS) v += bias[n];
      C[(long)m * ldc + n] = v;
    }
  }
}

// ---------------- split-bf16 MFMA GEMM, pre-split A: C = A * B^T (+bias) ----
template <int AMODE, int BH, int HASBIAS>
__global__ __launch_bounds__(256) void mgemm_k(const unsigned short* __restrict__ AH,
                                               const unsigned short* __restrict__ AL,
                                               int lda, int at0,
                                               const float* __restrict__ B,
                                               const float* __restrict__ bias,
                                               float* __restrict__ C, int ldc, int K) {
  __shared__ __align__(16) unsigned short Ah[64 * 40], Al[64 * 40], Bh[64 * 40], Bl[64 * 40];
  int tid = threadIdx.x;
  int m0 = blockIdx.x * 64, n0 = blockIdx.y * 64;
  int srow = tid >> 2, skoff = (tid & 3) * 8;
  int am = m0 + srow;
  long arow = (AMODE == 1) ? ((long)(am & 31) * 256 + at0 + (am >> 5)) : (long)am;
  const unsigned short* aptrH = AH + arow * (long)lda;
  const unsigned short* aptrL = AL + arow * (long)lda;
  int bn = n0 + srow;
  long gsrc;
  if (BH > 0) gsrc = (long)(bn & 3) * BH + (bn >> 2);
  else gsrc = bn;
  const float* bptr = B + gsrc * (long)K;

  int lane = tid & 63, wv = tid >> 6;
  int wm = (wv >> 1) * 32, wn = (wv & 1) * 32;
  int fr = lane & 15, fk = (lane >> 4) * 8;
  int rbase = (lane >> 4) * 4;

  f32x4 acc[2][2] = {};
  for (int k0 = 0; k0 < K; k0 += 32) {
    int kb = k0 + skoff;
    uint4 vh, vl;
    unsigned short hb[8] __attribute__((aligned(16))), lb[8] __attribute__((aligned(16)));
    if (kb + 8 <= K) {
      vh = *(const uint4*)(aptrH + kb);
      vl = *(const uint4*)(aptrL + kb);
      float4 b0 = *(const float4*)(bptr + kb);
      float4 b1 = *(const float4*)(bptr + kb + 4);
      float bv[8] = {b0.x, b0.y, b0.z, b0.w, b1.x, b1.y, b1.z, b1.w};
#pragma unroll
      for (int e = 0; e < 8; e++) splitf(bv[e], hb[e], lb[e]);
    } else {
      unsigned short ea[8] __attribute__((aligned(16))), el[8] __attribute__((aligned(16)));
#pragma unroll
      for (int e = 0; e < 8; e++) {
        int k = kb + e;
        ea[e] = (k < K) ? aptrH[k] : 0;
        el[e] = (k < K) ? aptrL[k] : 0;
        float bvv = (k < K) ? bptr[k] : 0.f;
        splitf(bvv, hb[e], lb[e]);
      }
      vh = *(const uint4*)ea;
      vl = *(const uint4*)el;
    }
    __syncthreads();
    *(uint4*)&Ah[srow * 40 + skoff] = vh;
    *(uint4*)&Al[srow * 40 + skoff] = vl;
    *(uint4*)&Bh[srow * 40 + skoff] = *(const uint4*)hb;
    *(uint4*)&Bl[srow * 40 + skoff] = *(const uint4*)lb;
    __syncthreads();
    bf16x8 fah[2], fal[2], fbh[2], fbl[2];
#pragma unroll
    for (int i = 0; i < 2; i++) {
      fah[i] = *(const bf16x8*)&Ah[(wm + i * 16 + fr) * 40 + fk];
      fal[i] = *(const bf16x8*)&Al[(wm + i * 16 + fr) * 40 + fk];
      fbh[i] = *(const bf16x8*)&Bh[(wn + i * 16 + fr) * 40 + fk];
      fbl[i] = *(const bf16x8*)&Bl[(wn + i * 16 + fr) * 40 + fk];
    }
#pragma unroll
    for (int i = 0; i < 2; i++)
#pragma unroll
      for (int j = 0; j < 2; j++) {
        acc[i][j] = __builtin_amdgcn_mfma_f32_16x16x32_bf16(fah[i], fbh[j], acc[i][j], 0, 0, 0);
        acc[i][j] = __builtin_amdgcn_mfma_f32_16x16x32_bf16(fah[i], fbl[j], acc[i][j], 0, 0, 0);
        acc[i][j] = __builtin_amdgcn_mfma_f32_16x16x32_bf16(fal[i], fbh[j], acc[i][j], 0, 0, 0);
      }
  }
#pragma unroll
  for (int i = 0; i < 2; i++)
#pragma unroll
    for (int j = 0; j < 2; j++)
#pragma unroll
      for (int r = 0; r < 4; r++) {
        int m = m0 + wm + i * 16 + rbase + r;
        int n = n0 + wn + j * 16 + fr;
        float v = acc[i][j][r];
        if (HASBIAS) {
          long gs = (BH > 0) ? ((long)(n & 3) * BH + (n >> 2)) : (long)n;
          v += bias[gs];
        }
        C[(long)m * ldc + n] = v;
      }
}

// ---------------- char-encoder fused step (pre-split A, MFMA, LSTM cell) ----
template <int K1>
__global__ __launch_bounds__(256) void mstep_k(
    const unsigned short* __restrict__ xFH, const unsigned short* __restrict__ xFL,
    const unsigned short* __restrict__ xBH, const unsigned short* __restrict__ xBL,
    int xstride,
    const float* __restrict__ Wx, const float* __restrict__ Wh,
    const float* __restrict__ bias,
    const unsigned short* __restrict__ hInH, const unsigned short* __restrict__ hInL,
    unsigned short* __restrict__ hOutH, unsigned short* __restrict__ hOutL,
    float* __restrict__ c_st,
    unsigned short* __restrict__ outH, unsigned short* __restrict__ outL,
    int out_stride, int tF, int tB) {
  __shared__ __align__(16) char smem[20480];
  unsigned short* Ah = (unsigned short*)smem;
  unsigned short* Al = Ah + 2560;
  unsigned short* Bh = Ah + 5120;
  unsigned short* Bl = Ah + 7680;
  float* gbuf = (float*)smem;  // [64][68] after MFMA loop (17408 B)

  int tid = threadIdx.x;
  int m0 = blockIdx.x * 64, n0 = blockIdx.y * 64;
  int dir = n0 >> 11;
  int nn0 = n0 & 2047;
  int srow = tid >> 2, skoff = (tid & 3) * 8;

  int am = m0 + srow;
  const unsigned short* axH = dir ? xBH : xFH;
  const unsigned short* axL = dir ? xBL : xFL;
  const unsigned short* arow_xH = axH + (long)am * xstride;
  const unsigned short* arow_xL = axL + (long)am * xstride;
  const unsigned short* arow_hH = hInH + (long)dir * 262144 + (long)am * 512;
  const unsigned short* arow_hL = hInL + (long)dir * 262144 + (long)am * 512;

  int bn = nn0 + srow;
  long gsrc = (long)dir * 2048 + (bn & 3) * 512 + (bn >> 2);
  const float* brow_x = Wx + gsrc * (long)K1;
  const float* brow_h = Wh + gsrc * 512L;

  int lane = tid & 63, wv = tid >> 6;
  int wm = (wv >> 1) * 32, wn = (wv & 1) * 32;
  int fr = lane & 15, fk = (lane >> 4) * 8;
  int rbase = (lane >> 4) * 4;

  f32x4 acc[2][2] = {};
  const int K = K1 + 512;
  for (int k0 = 0; k0 < K; k0 += 32) {
    int kb = k0 + skoff;
    uint4 vh, vl;
    const float* bp;
    if (kb < K1) {
      vh = *(const uint4*)(arow_xH + kb);
      vl = *(const uint4*)(arow_xL + kb);
      bp = brow_x + kb;
    } else {
      vh = *(const uint4*)(arow_hH + (kb - K1));
      vl = *(const uint4*)(arow_hL + (kb - K1));
      bp = brow_h + (kb - K1);
    }
    float4 b0 = *(const float4*)bp;
    float4 b1 = *(const float4*)(bp + 4);
    float bv[8] = {b0.x, b0.y, b0.z, b0.w, b1.x, b1.y, b1.z, b1.w};
    unsigned short hb[8] __attribute__((aligned(16))), lb[8] __attribute__((aligned(16)));
#pragma unroll
    for (int e = 0; e < 8; e++) splitf(bv[e], hb[e], lb[e]);
    __syncthreads();
    *(uint4*)&Ah[srow * 40 + skoff] = vh;
    *(uint4*)&Al[srow * 40 + skoff] = vl;
    *(uint4*)&Bh[srow * 40 + skoff] = *(const uint4*)hb;
    *(uint4*)&Bl[srow * 40 + skoff] = *(const uint4*)lb;
    __syncthreads();
    bf16x8 fah[2], fal[2], fbh[2], fbl[2];
#pragma unroll
    for (int i = 0; i < 2; i++) {
      fah[i] = *(const bf16x8*)&Ah[(wm + i * 16 + fr) * 40 + fk];
      fal[i] = *(const bf16x8*)&Al[(wm + i * 16 + fr) * 40 + fk];
      fbh[i] = *(const bf16x8*)&Bh[(wn + i * 16 + fr) * 40 + fk];
      fbl[i] = *(const bf16x8*)&Bl[(wn + i * 16 + fr) * 40 + fk];
    }
#pragma unroll
    for (int i = 0; i < 2; i++)
#pragma unroll
      for (int j = 0; j < 2; j++) {
        acc[i][j] = __builtin_amdgcn_mfma_f32_16x16x32_bf16(fah[i], fbh[j], acc[i][j], 0, 0, 0);
        acc[i][j] = __builtin_amdgcn_mfma_f32_16x16x32_bf16(fah[i], fbl[j], acc[i][j], 0, 0, 0);
        acc[i][j] = __builtin_amdgcn_mfma_f32_16x16x32_bf16(fal[i], fbh[j], acc[i][j], 0, 0, 0);
      }
  }
  __syncthreads();  // tiles dead; reuse LDS as gate buffer
#pragma unroll
  for (int i = 0; i < 2; i++)
#pragma unroll
    for (int j = 0; j < 2; j++)
#pragma unroll
      for (int r = 0; r < 4; r++)
        gbuf[(wm + i * 16 + rbase + r) * 68 + (wn + j * 16 + fr)] = acc[i][j][r];
  __syncthreads();

  int ug0 = nn0 >> 2;
  int t = dir ? tB : tF;
  for (int it = tid; it < 1024; it += 256) {
    int r = it >> 4, ul = it & 15;
    int seq = m0 + r, ug = ug0 + ul;
    float gi = gbuf[r * 68 + ul * 4 + 0] + bias[dir * 2048 + ug];
    float gf = gbuf[r * 68 + ul * 4 + 1] + bias[dir * 2048 + 512 + ug];
    float gg = gbuf[r * 68 + ul * 4 + 2] + bias[dir * 2048 + 1024 + ug];
    float go = gbuf[r * 68 + ul * 4 + 3] + bias[dir * 2048 + 1536 + ug];
    long ci = (long)dir * 262144 + (long)seq * 512 + ug;
    float c = sigf(gf) * c_st[ci] + sigf(gi) * tanhf(gg);
    float h = sigf(go) * tanhf(c);
    c_st[ci] = c;
    unsigned short hh, hl;
    splitf(h, hh, hl);
    hOutH[ci] = hh;
    hOutL[ci] = hl;
    long oo = ((long)seq * 16 + t) * out_stride + dir * 512 + ug;
    outH[oo] = hh;
    outL[oo] = hl;
  }
}

// ---------------- sentence recurrent ----------------
__global__ __launch_bounds__(256) void sent_rec_k(const float* __restrict__ pre,
                                                  const float* __restrict__ WhT,
                                                  float* __restrict__ out) {
  int blk = blockIdx.x;
  int n = blk & 31, dir = blk >> 5;
  int tid = threadIdx.x;
  __shared__ float hls[256];
  __shared__ float gls[1024];
  float c = 0.f;
  hls[tid] = 0.f;
  __syncthreads();
  const float* whbase = WhT + (long)dir * 256 * 1024;
  int g4 = tid * 4;
  for (int s = 0; s < 16; s++) {
    int t = dir ? (15 - s) : s;
    const float* prow = pre + (long)(n * 16 + t) * 2048 + dir * 1024;
    float ax = 0.f, ay = 0.f, az = 0.f, aw = 0.f;
#pragma unroll 4
    for (int k = 0; k < 256; k++) {
      float hk = hls[k];
      float4 w = *(const float4*)(whbase + (long)k * 1024 + g4);
      ax += hk * w.x; ay += hk * w.y; az += hk * w.z; aw += hk * w.w;
    }
    float4 p = *(const float4*)(prow + g4);
    gls[g4 + 0] = ax + p.x; gls[g4 + 1] = ay + p.y;
    gls[g4 + 2] = az + p.z; gls[g4 + 3] = aw + p.w;
    __syncthreads();
    float gi = gls[tid], gf = gls[256 + tid], gg = gls[512 + tid], go = gls[768 + tid];
    c = sigf(gf) * c + sigf(gi) * tanhf(gg);
    float h = sigf(go) * tanhf(c);
    __syncthreads();
    hls[tid] = h;
    out[(long)n * 8192 + (long)t * 512 + dir * 256 + tid] = h;
    __syncthreads();
  }
}

// load one K-step of A(H/L) + B(split to hb/lb) into registers
#define GLOADK(k0v)                                                         \
  {                                                                         \
    int kb = (k0v) + skoff;                                                 \
    if (kb + 8 <= 1544) {                                                   \
      vh = *(const uint4*)(aptrH + kb);                                     \
      vl = *(const uint4*)(aptrL + kb);                                     \
      float4 b0 = *(const float4*)(bptr + kb);                              \
      float4 b1 = *(const float4*)(bptr + kb + 4);                          \
      float bv[8] = {b0.x, b0.y, b0.z, b0.w, b1.x, b1.y, b1.z, b1.w};       \
      _Pragma("unroll") for (int e = 0; e < 8; e++)                         \
          splitf(bv[e], hb[e], lb[e]);                                      \
    } else {                                                                \
      unsigned short ea[8] __attribute__((aligned(16)));                    \
      unsigned short el[8] __attribute__((aligned(16)));                    \
      _Pragma("unroll") for (int e = 0; e < 8; e++) {                       \
        int k = kb + e;                                                     \
        ea[e] = (k < 1544) ? aptrH[k] : 0;                                  \
        el[e] = (k < 1544) ? aptrL[k] : 0;                                  \
        float bvv = (k < 1544) ? bptr[k] : 0.f;                             \
        splitf(bvv, hb[e], lb[e]);                                          \
      }                                                                     \
      vh = *(const uint4*)ea;                                               \
      vl = *(const uint4*)el;                                               \
    }                                                                       \
  }

#define WLDS(bufp)                                                          \
  {                                                                         \
    unsigned short* W_ = (bufp);                                            \
    *(uint4*)&W_[srow * 40 + skoff] = vh;                                   \
    *(uint4*)&W_[2560 + srow * 40 + skoff] = vl;                            \
    *(uint4*)&W_[5120 + srow * 40 + skoff] = *(const uint4*)hb;             \
    *(uint4*)&W_[7680 + srow * 40 + skoff] = *(const uint4*)lb;             \
  }

// ---------------- fused decoder + next-chunk Wx GEMM ------------------------
// 256 blocks x 256 thr.
// Blocks 0-127: R3-config persistent decoder for chunk at tbase (LDS weights
//   128 KB, 4 waves x K-quarters, batched 16-load sc1 h-exchange, fence-free
//   loop, 2-level barrier with absolute-step targets, cnt memset once).
// Blocks 128-255: dec_Wx GEMM for chunk ch+1 (1024 64x64 tiles, 8 per block,
//   fixed m-tile per block). R7: double-buffered LDS, ONE barrier per K-step,
//   k+1 loads prefetched into registers right after the barrier and consumed
//   at the write stage -> global latency hides under frag-reads + 12 MFMAs.
//   (R6: the old 2-barrier loop at 1 block/CU was the critical path, at
//   exactly the no-TLP 4x scaling of mgemm's 86 us: 344 predicted, 333
//   measured.)
__global__ __launch_bounds__(256, 1) void dec_fused_k(
    const unsigned short* __restrict__ WhFH, const unsigned short* __restrict__ WhFL,
    const float* __restrict__ pre,
    unsigned short* __restrict__ hH, unsigned short* __restrict__ hL,
    float* __restrict__ c_st, float* __restrict__ dec_out,
    int* __restrict__ cnt, int tbase,
    const unsigned short* __restrict__ AH, const unsigned short* __restrict__ AL,
    const float* __restrict__ Bw, const float* __restrict__ bias,
    float* __restrict__ pre_nxt, int at0, int do_gemm) {
  extern __shared__ char smem[];
  int tid = threadIdx.x, bid = blockIdx.x;

  if (bid < 128) {
    // ======================= decoder (R3 config) =======================
    unsigned short* wHs = (unsigned short*)smem;            // 64 KB
    unsigned short* wLs = (unsigned short*)(smem + 65536);  // 64 KB
    float* gbuf = (float*)(smem + 131072);                  // [4][32][33]

    int lane = tid & 63, kh = tid >> 6;
    int fr = lane & 15, fq = (lane >> 4) & 3;
    int grp = bid >> 3;  // 16 groups of 8 blocks

    {
      const unsigned short* gH = WhFH + (long)bid * 32768;
      const unsigned short* gL = WhFL + (long)bid * 32768;
      for (int o = tid * 8; o < 32768; o += 2048) {
        *(uint4*)&wHs[o] = *(const uint4*)&gH[o];
        *(uint4*)&wLs[o] = *(const uint4*)&gL[o];
      }
    }

    int bb = tid >> 2, up = tid & 3;
    int u0 = bid * 8 + up * 2;
    long co = (long)bb * 1024 + u0;
    float c0 = 0.f, c1 = 0.f;
    if (tid < 128) {
      float2 cc = *(const float2*)&c_st[co];
      c0 = cc.x;
      c1 = cc.y;
    }
    __syncthreads();

    for (int tl = 0; tl < 32; tl++) {
      int t = tbase + tl;
      const unsigned short* hInH = hH + (long)(t & 1) * 32768;
      const unsigned short* hInL = hL + (long)(t & 1) * 32768;
      unsigned short* hOutH = hH + (long)((t + 1) & 1) * 32768;
      unsigned short* hOutL = hL + (long)((t + 1) & 1) * 32768;

      float4 p0 = {0.f, 0.f, 0.f, 0.f}, p1 = {0.f, 0.f, 0.f, 0.f};
      if (tid < 128) {
        const float* pr = pre + ((long)tl * 32 + bb) * 4096 + bid * 32 + up * 8;
        p0 = *(const float4*)pr;
        p1 = *(const float4*)(pr + 4);
      }

      // all 32 h-fragment loads in flight, one waitcnt (batched sc1 loads)
      u32x4 hHr[2][8], hLr[2][8];
#pragma unroll
      for (int bh = 0; bh < 2; bh++)
#pragma unroll
        for (int i = 0; i < 8; i++) {
          long a = (long)(bh * 16 + fr) * 1024 + (kh * 8 + i) * 32 + fq * 8;
          ldg16_cc(hHr[bh][i], hInH + a);
          ldg16_cc(hLr[bh][i], hInL + a);
        }
      asm volatile("s_waitcnt vmcnt(0)");
      __builtin_amdgcn_sched_barrier(0);

      f32x4 acc[2][2] = {};  // [col-tile ct][batch-half bh]
#pragma unroll
      for (int i = 0; i < 8; i++) {
        int kt = kh * 8 + i;
#pragma unroll
        for (int ct = 0; ct < 2; ct++) {
          bf16x8 wh = *(const bf16x8*)&wHs[(ct * 32 + kt) * 512 + lane * 8];
          bf16x8 wl = *(const bf16x8*)&wLs[(ct * 32 + kt) * 512 + lane * 8];
#pragma unroll
          for (int bh = 0; bh < 2; bh++) {
            bf16x8 ah = __builtin_bit_cast(bf16x8, hHr[bh][i]);
            bf16x8 al = __builtin_bit_cast(bf16x8, hLr[bh][i]);
            acc[ct][bh] = __builtin_amdgcn_mfma_f32_16x16x32_bf16(ah, wh, acc[ct][bh], 0, 0, 0);
            acc[ct][bh] = __builtin_amdgcn_mfma_f32_16x16x32_bf16(ah, wl, acc[ct][bh], 0, 0, 0);
            acc[ct][bh] = __builtin_amdgcn_mfma_f32_16x16x32_bf16(al, wh, acc[ct][bh], 0, 0, 0);
          }
        }
      }
#pragma unroll
      for (int ct = 0; ct < 2; ct++)
#pragma unroll
        for (int bh = 0; bh < 2; bh++)
#pragma unroll
          for (int r = 0; r < 4; r++)
            gbuf[(kh * 32 + bh * 16 + fq * 4 + r) * 33 + ct * 16 + fr] = acc[ct][bh][r];
      __syncthreads();

      if (tid < 128) {
        float g[8];
#pragma unroll
        for (int e = 0; e < 8; e++) {
          float s = gbuf[bb * 33 + up * 8 + e];
#pragma unroll
          for (int q = 1; q < 4; q++) s += gbuf[(q * 32 + bb) * 33 + up * 8 + e];
          g[e] = s;
        }
        c0 = sigf(g[1] + p0.y) * c0 + sigf(g[0] + p0.x) * tanhf(g[2] + p0.z);
        float h0 = sigf(g[3] + p0.w) * tanhf(c0);
        c1 = sigf(g[5] + p1.y) * c1 + sigf(g[4] + p1.x) * tanhf(g[6] + p1.z);
        float h1 = sigf(g[7] + p1.w) * tanhf(c1);
        unsigned short h0h, h0l, h1h, h1l;
        splitf(h0, h0h, h0l);
        splitf(h1, h1h, h1l);
        unsigned ph = (unsigned)h0h | ((unsigned)h1h << 16);
        unsigned pl = (unsigned)h0l | ((unsigned)h1l << 16);
        __hip_atomic_store((unsigned*)(hOutH + co), ph, __ATOMIC_RELAXED,
                           __HIP_MEMORY_SCOPE_AGENT);
        __hip_atomic_store((unsigned*)(hOutL + co), pl, __ATOMIC_RELAXED,
                           __HIP_MEMORY_SCOPE_AGENT);
        float2 hv;
        hv.x = h0;
        hv.y = h1;
        *(float2*)&dec_out[((long)bb * 256 + t) * 1024 + u0] = hv;
      }
      __syncthreads();  // drains vmcnt -> all h stores at LLC

      // barrier every step; absolute-step targets (cnt monotonic over chunks)
      if (tid == 0) {
        int old = __hip_atomic_fetch_add(&cnt[grp * 32], 1, __ATOMIC_RELAXED,
                                         __HIP_MEMORY_SCOPE_AGENT);
        if (old == 8 * t + 7)
          __hip_atomic_fetch_add(&cnt[512], 1, __ATOMIC_RELAXED,
                                 __HIP_MEMORY_SCOPE_AGENT);
        while (__hip_atomic_load(&cnt[512], __ATOMIC_RELAXED,
                                 __HIP_MEMORY_SCOPE_AGENT) < 16 * (t + 1))
          __builtin_amdgcn_s_sleep(1);
      }
      __syncthreads();
    }
    if (tid < 128) {
      float2 cv;
      cv.x = c0;
      cv.y = c1;
      *(float2*)&c_st[co] = cv;
    }
  } else if (do_gemm) {
    // ====== next-chunk dec_Wx GEMM: double-buffered, 1 barrier/K-step ======
    // LDS: 2 buffers x [Ah|Al|Bh|Bl] x 2560 shorts = 40960 B
    unsigned short* lbase = (unsigned short*)smem;
    const int K = 1544;
    int srow = tid >> 2, skoff = (tid & 3) * 8;
    int lane = tid & 63, wv = tid >> 6;
    int wm = (wv >> 1) * 32, wn = (wv & 1) * 32;
    int fr = lane & 15, fk = (lane >> 4) * 8;
    int rbase = (lane >> 4) * 4;
    int gid = bid - 128;

    for (int t8 = 0; t8 < 8; t8++) {
      int tile = gid + 128 * t8;
      int m0 = (tile & 15) * 64, n0 = (tile >> 4) * 64;
      int am = m0 + srow;
      long arow = (long)(am & 31) * 256 + at0 + (am >> 5);
      const unsigned short* aptrH = AH + arow * 1544L;
      const unsigned short* aptrL = AL + arow * 1544L;
      int bn = n0 + srow;
      long gsrc = (long)(bn & 3) * 1024 + (bn >> 2);
      const float* bptr = Bw + gsrc * 1544L;

      f32x4 acc[2][2] = {};
      uint4 vh, vl;
      unsigned short hb[8] __attribute__((aligned(16)));
      unsigned short lb[8] __attribute__((aligned(16)));

      // prologue: k=0 into regs, then buf0 (sync first: prior tile reads done)
      GLOADK(0);
      __syncthreads();
      WLDS(lbase);
      int cur = 0;

      for (int k0 = 0; k0 < K; k0 += 32) {
        __syncthreads();  // buf[cur] visible; buf[cur^1] free (read last iter)
        bool more = (k0 + 32 < K);
        if (more) GLOADK(k0 + 32);  // prefetch k+1; consumed at write stage
        unsigned short* Bf = lbase + cur * 10240;
        bf16x8 fah[2], fal[2], fbh[2], fbl[2];
#pragma unroll
        for (int i = 0; i < 2; i++) {
          fah[i] = *(const bf16x8*)&Bf[(wm + i * 16 + fr) * 40 + fk];
          fal[i] = *(const bf16x8*)&Bf[2560 + (wm + i * 16 + fr) * 40 + fk];
          fbh[i] = *(const bf16x8*)&Bf[5120 + (wn + i * 16 + fr) * 40 + fk];
          fbl[i] = *(const bf16x8*)&Bf[7680 + (wn + i * 16 + fr) * 40 + fk];
        }
#pragma unroll
        for (int i = 0; i < 2; i++)
#pragma unroll
          for (int j = 0; j < 2; j++) {
            acc[i][j] = __builtin_amdgcn_mfma_f32_16x16x32_bf16(fah[i], fbh[j], acc[i][j], 0, 0, 0);
            acc[i][j] = __builtin_amdgcn_mfma_f32_16x16x32_bf16(fah[i], fbl[j], acc[i][j], 0, 0, 0);
            acc[i][j] = __builtin_amdgcn_mfma_f32_16x16x32_bf16(fal[i], fbh[j], acc[i][j], 0, 0, 0);
          }
        if (more) {
          WLDS(lbase + (cur ^ 1) * 10240);
          cur ^= 1;
        }
      }
#pragma unroll
      for (int i = 0; i < 2; i++)
#pragma unroll
        for (int j = 0; j < 2; j++)
#pragma unroll
          for (int r = 0; r < 4; r++) {
            int m = m0 + wm + i * 16 + rbase + r;
            int n = n0 + wn + j * 16 + fr;
            long gs = (long)(n & 3) * 1024 + (n >> 2);
            pre_nxt[(long)m * 4096 + n] = acc[i][j][r] + bias[gs];
          }
    }
  }
}

// ---------------- attention ----------------
__global__ __launch_bounds__(256) void attn_k(const float* __restrict__ sent_enc,
                                              const float* __restrict__ qbuf,
                                              const int* __restrict__ words,
                                              float* __restrict__ attn_out,
                                              unsigned short* __restrict__ fH,
                                              unsigned short* __restrict__ fL) {
  int b = blockIdx.x >> 4;
  int i = blockIdx.x & 15;
  int tid = threadIdx.x;
  __shared__ float se[16][512];
  __shared__ float qq[16][512];
  __shared__ float sc[16][16];
  __shared__ int kv[16];
  if (tid < 16) kv[tid] = 0;
  __syncthreads();
  {
    int j = tid >> 4, c = tid & 15;
    if (words[(b * 16 + j) * 16 + c] != 0) atomicOr(&kv[j], 1);
  }
  for (int idx = tid; idx < 16 * 128; idx += 256) {
    int j = idx >> 7, d4 = idx & 127;
    *(float4*)&se[j][d4 * 4] = *(const float4*)(sent_enc + (long)(b * 16 + j) * 512 + d4 * 4);
  }
  for (int idx = tid; idx < 16 * 128; idx += 256) {
    int c = idx >> 7, d4 = idx & 127;
    *(float4*)&qq[c][d4 * 4] = *(const float4*)(qbuf + (long)(b * 256 + i * 16 + c) * 512 + d4 * 4);
  }
  __syncthreads();
  int c = tid >> 4, j = tid & 15;
  {
    float s = 0.f;
#pragma unroll 4
    for (int k = 0; k < 512; k++) s += qq[c][k] * se[j][k];
    bool valid = (kv[j] != 0) && (j != i);
    sc[c][j] = valid ? s : -1e9f;
  }
  __syncthreads();
  float m = -INFINITY;
#pragma unroll
  for (int t = 0; t < 16; t++) m = fmaxf(m, sc[c][t]);
  float den = 0.f;
#pragma unroll
  for (int t = 0; t < 16; t++) den += expf(sc[c][t] - m);
  float a = expf(sc[c][j] - m) / den;
  __syncthreads();
  sc[c][j] = a;
  attn_out[((long)((b * 16 + i) * 16 + c)) * 16 + j] = a;
  __syncthreads();
  {
    int part = tid & 15;
    int cc = tid >> 4;
    for (int d = part * 32; d < part * 32 + 32; d++) {
      float v = 0.f;
#pragma unroll
      for (int jj = 0; jj < 16; jj++) v += sc[cc][jj] * se[jj][d];
      long o = (long)(b * 256 + i * 16 + cc) * 1544 + d;
      unsigned short hh, hl;
      splitf(v, hh, hl);
      fH[o] = hh;
      fL[o] = hl;
    }
  }
}

// ---------------------------------------------------------------------------
extern "C" void kernel_launch(void* const* d_in, const int* in_sizes, int n_in,
                              void* d_out, int out_size, void* d_ws, size_t ws_size,
                              hipStream_t stream) {
  const int* sents = (const int*)d_in[0];
  const int* words = (const int*)d_in[1];
  const int* labels = (const int*)d_in[2];
  const float* word_embs = (const float*)d_in[3];
  const float* char_table = (const float*)d_in[4];
  const float* sent_Wx0 = (const float*)d_in[5];
  const float* sent_Wh0 = (const float*)d_in[6];
  const float* sent_b0 = (const float*)d_in[7];
  const float* sent_Wx1 = (const float*)d_in[8];
  const float* sent_Wh1 = (const float*)d_in[9];
  const float* sent_b1 = (const float*)d_in[10];
  const float* word_Wx0 = (const float*)d_in[11];
  const float* word_Wh0 = (const float*)d_in[12];
  const float* word_b0 = (const float*)d_in[13];
  const float* word_Wx1 = (const float*)d_in[14];
  const float* word_Wh1 = (const float*)d_in[15];
  const float* word_b1 = (const float*)d_in[16];
  const float* attn_Wq = (const float*)d_in[17];
  const float* dec_Wx = (const float*)d_in[18];
  const float* dec_Wh = (const float*)d_in[19];
  const float* dec_b = (const float*)d_in[20];
  const float* cls_W = (const float*)d_in[21];
  const float* cls_b = (const float*)d_in[22];

  char* base = (char*)d_ws;
  // ---- Slot Z (early phase; overlaid by WhF pairs during decoder) ---------
  float* wembs   = (float*)(base + 0);          // 153600 fl
  float* preS    = (float*)(base + 614400);     // 1048576 fl
  float* hs0     = (float*)(base + 4808704);    // 262144 fl
  float* WhT0    = (float*)(base + 5857280);    // 524288 fl
  float* WhT1    = (float*)(base + 7954432);    // 524288 fl
  float* sentenc = (float*)(base + 10051584);   // 262144 fl
  unsigned short* hcharH = (unsigned short*)(base + 11100160);  // 1048576 us
  unsigned short* hcharL = (unsigned short*)(base + 13197312);  // 1048576 us
  float* cchar   = (float*)(base + 15294464);   // 524288 fl  (Z ends 17391616)
  unsigned short* WhFH = (unsigned short*)(base + 0);        // 4194304 us (overlay)
  unsigned short* WhFL = (unsigned short*)(base + 8388608);  // 4194304 us
  // ---- Slot W: finalb pairs ----------------------------------------------
  unsigned short* finalbH = (unsigned short*)(base + 17391616);  // 12648448 us
  unsigned short* finalbL = (unsigned short*)(base + 42688512);  // 12648448 us
  // ---- Slot Y: q (attn) then pre buffer 0 (decoder), 4194304 fl -----------
  float* qbuf = (float*)(base + 67985408);
  float* pre0 = qbuf;
  // ---- WqT ----------------------------------------------------------------
  float* WqT = (float*)(base + 84762624);       // 524288 fl
  // ---- Slot X (char phase; overlaid by decoder/classifier buffers) --------
  unsigned short* charinH = (unsigned short*)(base + 86859776);   // 4456448 us
  unsigned short* charinL = (unsigned short*)(base + 95772672);   // 4456448 us
  unsigned short* hc0H = (unsigned short*)(base + 104685568);     // 8388608 us
  unsigned short* hc0L = (unsigned short*)(base + 121462784);     // 8388608 us (X ends 138240000)
  float* dec_out = (float*)(base + 86859776);                     // 8388608 fl (overlay)
  unsigned short* hdecH = (unsigned short*)(base + 120414208);    // 65536 us
  unsigned short* hdecL = (unsigned short*)(base + 120545280);    // 65536 us
  float* c_dec = (float*)(base + 120676352);                      // 32768 fl
  float* clsWT = (float*)(base + 120807424);                      // 15360 fl
  int* cnt = (int*)(base + 120868864);                            // 1024 int (barrier)
  float* pre1 = (float*)(base + 121462784);                       // 4194304 fl (overlays dead hc0L)

  float* dout = (float*)d_out;
  float* diac = dout;              // 8192 x 15
  float* attnmap = dout + 122880;  // 32 x 16 x 16 x 16

  // one-time: allow 144.5 KB dynamic LDS on the fused decoder
  static bool s_dec_attr = false;
  if (!s_dec_attr) {
    hipFuncSetAttribute(reinterpret_cast<const void*>(dec_fused_k),
                        hipFuncAttributeMaxDynamicSharedMemorySize, 147968);
    s_dec_attr = true;
  }

  // ---- weight preprocessing (sentence + attention) --------------------------
  transpose_k<<<dim3(32, 8), 256, 0, stream>>>(sent_Wh0, WhT0, 1024, 256, 0);
  transpose_k<<<dim3(32, 8), 256, 0, stream>>>(sent_Wh0 + 262144, WhT0 + 262144, 1024, 256, 0);
  transpose_k<<<dim3(32, 8), 256, 0, stream>>>(sent_Wh1, WhT1, 1024, 256, 0);
  transpose_k<<<dim3(32, 8), 256, 0, stream>>>(sent_Wh1 + 262144, WhT1 + 262144, 1024, 256, 0);
  transpose_k<<<dim3(32, 16), 256, 0, stream>>>(attn_Wq, WqT, 1024, 512, 0);

  // ---- sentence encoder -----------------------------------------------------
  embed_k<<<600, 256, 0, stream>>>(sents, word_embs, wembs);
  gemm_k<1><<<dim3(8, 32), 256, 0, stream>>>(wembs, 300, sent_Wx0, sent_b0,
                                             preS, 2048, 512, 2048, 300);
  sent_rec_k<<<64, 256, 0, stream>>>(preS, WhT0, hs0);
  gemm_k<1><<<dim3(8, 32), 256, 0, stream>>>(hs0, 512, sent_Wx1, sent_b1,
                                             preS, 2048, 512, 2048, 512);
  sent_rec_k<<<64, 256, 0, stream>>>(preS, WhT1, sentenc);

  // ---- char encoder ---------------------------------------------------------
  charin_k<<<17408, 256, 0, stream>>>(words, char_table, sentenc, charinH, charinL);

  hipMemsetAsync(base + 11100160, 0, 6291456, stream);  // hcharH/L + cchar
  for (int s = 0; s < 16; s++) {
    int p = s & 1;
    mstep_k<544><<<dim3(8, 64), 256, 0, stream>>>(
        charinH + s * 544, charinL + s * 544,
        charinH + (15 - s) * 544, charinL + (15 - s) * 544, 16 * 544,
        word_Wx0, word_Wh0, word_b0,
        hcharH + p * 524288, hcharL + p * 524288,
        hcharH + (p ^ 1) * 524288, hcharL + (p ^ 1) * 524288, cchar,
        hc0H, hc0L, 1024, s, 15 - s);
  }
  hipMemsetAsync(base + 11100160, 0, 6291456, stream);
  for (int s = 0; s < 16; s++) {
    int p = s & 1;
    mstep_k<1024><<<dim3(8, 64), 256, 0, stream>>>(
        hc0H + s * 1024, hc0L + s * 1024,
        hc0H + (15 - s) * 1024, hc0L + (15 - s) * 1024, 16 * 1024,
        word_Wx1, word_Wh1, word_b1,
        hcharH + p * 524288, hcharL + p * 524288,
        hcharH + (p ^ 1) * 524288, hcharL + (p ^ 1) * 524288, cchar,
        finalbH + 512, finalbL + 512, 1544, s, 15 - s);
  }

  // ---- attention ------------------------------------------------------------
  mgemm_k<0, 0, 0><<<dim3(128, 8), 256, 0, stream>>>(finalbH + 512, finalbL + 512, 1544, 0,
                                                     WqT, nullptr, qbuf, 512, 1024);
  attn_k<<<512, 256, 0, stream>>>(sentenc, qbuf, words, attnmap, finalbH, finalbL);
  labels_k<<<256, 256, 0, stream>>>(labels, finalbH, finalbL);

  // ---- decoder: chunk0 pre, then 8 fused (decoder ch ∥ GEMM ch+1) ----------
  decwh_prep_k<<<16384, 256, 0, stream>>>(dec_Wh, WhFH, WhFL);  // overlays Slot Z
  hipMemsetAsync(base + 120414208, 0, 393216, stream);          // hdecH/L + c_dec
  hipMemsetAsync(cnt, 0, 4096, stream);                         // barrier counters (once)
  mgemm_k<1, 1024, 1><<<dim3(16, 64), 256, 0, stream>>>(finalbH, finalbL, 1544, 0,
                                                        dec_Wx, dec_b, pre0, 4096, 1544);
  float* preBuf[2] = {pre0, pre1};
  for (int ch = 0; ch < 8; ch++) {
    dec_fused_k<<<256, 256, 147968, stream>>>(
        WhFH, WhFL, preBuf[ch & 1], hdecH, hdecL, c_dec, dec_out, cnt, ch * 32,
        finalbH, finalbL, dec_Wx, dec_b, preBuf[(ch + 1) & 1], (ch + 1) * 32,
        (ch < 7) ? 1 : 0);
  }

  // ---- classifier -----------------------------------------------------------
  transpose_k<<<dim3(32, 1), 256, 0, stream>>>(cls_W, clsWT, 1024, 15, 0);
  gemm_k<1><<<dim3(128, 1), 256, 0, stream>>>(dec_out, 1024, clsWT, cls_b,
                                              diac, 15, 8192, 15, 1024);
}

// Round 9
// 4650.142 us; speedup vs baseline: 1.0231x; 1.0231x over previous
//
#include <hip/hip_runtime.h>
#include <math.h>

// ---------------------------------------------------------------------------
// DiacritizerD3: split-bf16 MFMA pipeline. Decoder = R3-config persistent
// kernel FUSED with next-chunk dec_Wx GEMM (R7 structure, unchanged: the
// fused dispatch is decoder-capped at ~333us; R6+R7 proved GEMM-half changes
// are invisible). R8 (resubmit after infra failure; overlays re-audited):
// char-encoder weights (Wx0/Wh0/Wx1/Wh1) and WqT pre-split ONCE into bf16
// H/L pairs, removing the 8x per-thread-per-K-step splitf (~48 VALU ops,
// ~half the K-loop cost) from all 32 mstep launches and the qbuf GEMM.
// B=32, TS=16, TW=16, SENT_H=256 (DIN=512), WORD_H=512 (DQ=DEC_H=1024),
// CDIM=32, WDIM=300, DEC_IN=1544.
// ---------------------------------------------------------------------------

typedef __attribute__((ext_vector_type(8))) __bf16 bf16x8;
typedef __attribute__((ext_vector_type(4))) float f32x4;
typedef __attribute__((ext_vector_type(4))) unsigned u32x4;

__device__ __forceinline__ float sigf(float x) { return 1.0f / (1.0f + expf(-x)); }

__device__ __forceinline__ unsigned short bf16rn(float x) {
  unsigned u = __float_as_uint(x);
  return (unsigned short)((u + 0x7fffu + ((u >> 16) & 1u)) >> 16);
}
__device__ __forceinline__ void splitf(float x, unsigned short& h, unsigned short& l) {
  h = bf16rn(x);
  float fh = __uint_as_float((unsigned)h << 16);
  l = bf16rn(x - fh);
}

// cache-bypassing (L1+L2) 16B load via volatile asm: loads issue back-to-back
// and stay in flight; caller pays one s_waitcnt vmcnt(0).
__device__ __forceinline__ void ldg16_cc(u32x4& d, const void* p) {
  asm volatile("global_load_dwordx4 %0, %1, off sc0 sc1" : "=v"(d) : "v"(p));
}

#define FMA16(a, b, acc)                                                           \
  acc[0][0] += a.x * b.x; acc[0][1] += a.x * b.y; acc[0][2] += a.x * b.z; acc[0][3] += a.x * b.w; \
  acc[1][0] += a.y * b.x; acc[1][1] += a.y * b.y; acc[1][2] += a.y * b.z; acc[1][3] += a.y * b.w; \
  acc[2][0] += a.z * b.x; acc[2][1] += a.z * b.y; acc[2][2] += a.z * b.z; acc[2][3] += a.z * b.w; \
  acc[3][0] += a.w * b.x; acc[3][1] += a.w * b.y; acc[3][2] += a.w * b.z; acc[3][3] += a.w * b.w;

// ---------------- transpose ----------------
__global__ __launch_bounds__(256) void transpose_k(const float* __restrict__ in,
                                                   float* __restrict__ out,
                                                   int R, int C, int H) {
  __shared__ float tile[32][33];
  int r0 = blockIdx.x * 32, c0 = blockIdx.y * 32;
  int tx = threadIdx.x & 31, ty = threadIdx.x >> 5;
  for (int yy = ty; yy < 32; yy += 8) {
    int r = r0 + yy, c = c0 + tx;
    float v = 0.f;
    if (r < R && c < C) {
      int gs = H ? ((r & 3) * H + (r >> 2)) : r;
      v = in[(long)gs * C + c];
    }
    tile[yy][tx] = v;
  }
  __syncthreads();
  for (int yy = ty; yy < 32; yy += 8) {
    int c = c0 + yy, r = r0 + tx;
    if (r < R && c < C) out[(long)c * R + r] = tile[tx][yy];
  }
}

// ---------------- weight pre-split (elementwise, layout-preserving) ---------
__global__ void wprep_k(const float* __restrict__ W, unsigned short* __restrict__ H,
                        unsigned short* __restrict__ L, int n) {
  int idx = blockIdx.x * 256 + threadIdx.x;
  if (idx >= n) return;
  unsigned short h, l;
  splitf(W[idx], h, l);
  H[idx] = h;
  L[idx] = l;
}

// ---------------- embedding lookup ----------------
__global__ void embed_k(const int* __restrict__ sents, const float* __restrict__ word_embs,
                        float* __restrict__ wembs) {
  int idx = blockIdx.x * 256 + threadIdx.x;
  if (idx >= 512 * 300) return;
  int r = idx / 300, k = idx - r * 300;
  wembs[idx] = word_embs[(long)sents[r] * 300 + k];
}

// ---------------- char-encoder input build (writes bf16 hi/lo pairs) --------
__global__ void charin_k(const int* __restrict__ words, const float* __restrict__ char_table,
                         const float* __restrict__ sent_enc,
                         unsigned short* __restrict__ ciH, unsigned short* __restrict__ ciL) {
  int idx = blockIdx.x * 256 + threadIdx.x;
  if (idx >= 512 * 16 * 544) return;
  int k = idx % 544;
  int rc = idx / 544;
  int c = rc & 15, n = rc >> 4;
  int w = words[n * 16 + c];
  float v;
  if (k < 32) v = char_table[w * 32 + k];
  else v = (w != 0) ? sent_enc[n * 512 + (k - 32)] : 0.f;
  unsigned short h, l;
  splitf(v, h, l);
  ciH[idx] = h; ciL[idx] = l;
}

// ---------------- labels -> final[:,1536:1544] (pairs) ----------------------
__global__ void labels_k(const int* __restrict__ labels,
                         unsigned short* __restrict__ fH, unsigned short* __restrict__ fL) {
  int idx = blockIdx.x * 256 + threadIdx.x;
  if (idx >= 8192 * 8) return;
  int r = idx >> 3, l = idx & 7;
  long o = (long)r * 1544 + 1536 + l;
  fH[o] = bf16rn((float)labels[idx]);
  fL[o] = 0;
}

// ---------------- dec_Wh -> fragment-contiguous split layout ----------------
__global__ void decwh_prep_k(const float* __restrict__ dec_Wh,
                             unsigned short* __restrict__ WhFH,
                             unsigned short* __restrict__ WhFL) {
  long o = (long)blockIdx.x * 256 + threadIdx.x;
  if (o >= 4194304) return;
  int j = (int)(o & 7);
  int lane = (int)((o >> 3) & 63);
  int kt = (int)((o >> 9) & 31);
  int nt = (int)(o >> 14);
  int col = nt * 16 + (lane & 15);
  int gsrc = (col & 3) * 1024 + (col >> 2);
  int k = kt * 32 + ((lane >> 4) & 3) * 8 + j;
  float v = dec_Wh[(long)gsrc * 1024 + k];
  unsigned short h, l;
  splitf(v, h, l);
  WhFH[o] = h; WhFL[o] = l;
}

// ---------------- fp32 fallback GEMM (sentence Wx, classifier) --------------
template <int HASBIAS>
__global__ __launch_bounds__(256) void gemm_k(const float* __restrict__ A, int lda,
                                              const float* __restrict__ Bw,
                                              const float* __restrict__ bias,
                                              float* __restrict__ C, int ldc,
                                              int M, int N, int K) {
  __shared__ float As[32][64];
  __shared__ float Bs[32][64];
  int tid = threadIdx.x;
  int m0 = blockIdx.x * 64, n0 = blockIdx.y * 64;
  int tn = tid & 15, tm = tid >> 4;
  int lrow = tid >> 2, lk = (tid & 3) * 8;
  float acc[4][4] = {};
  int am = m0 + lrow;
  const float* aptr = A + (long)am * lda;
  bool mok = am < M;
  int bn = n0 + lrow;
  const float* bptr = Bw + (long)bn * K;
  bool nok = bn < N;

  for (int k0 = 0; k0 < K; k0 += 32) {
    int kb = k0 + lk;
    if (kb + 8 <= K) {
      if (mok) {
        float4 v0 = *(const float4*)(aptr + kb);
        float4 v1 = *(const float4*)(aptr + kb + 4);
        As[lk + 0][lrow] = v0.x; As[lk + 1][lrow] = v0.y; As[lk + 2][lrow] = v0.z; As[lk + 3][lrow] = v0.w;
        As[lk + 4][lrow] = v1.x; As[lk + 5][lrow] = v1.y; As[lk + 6][lrow] = v1.z; As[lk + 7][lrow] = v1.w;
      } else {
#pragma unroll
        for (int i = 0; i < 8; i++) As[lk + i][lrow] = 0.f;
      }
      if (nok) {
        float4 v0 = *(const float4*)(bptr + kb);
        float4 v1 = *(const float4*)(bptr + kb + 4);
        Bs[lk + 0][lrow] = v0.x; Bs[lk + 1][lrow] = v0.y; Bs[lk + 2][lrow] = v0.z; Bs[lk + 3][lrow] = v0.w;
        Bs[lk + 4][lrow] = v1.x; Bs[lk + 5][lrow] = v1.y; Bs[lk + 6][lrow] = v1.z; Bs[lk + 7][lrow] = v1.w;
      } else {
#pragma unroll
        for (int i = 0; i < 8; i++) Bs[lk + i][lrow] = 0.f;
      }
    } else {
#pragma unroll
      for (int i = 0; i < 8; i++) {
        int k = kb + i;
        As[lk + i][lrow] = (mok && k < K) ? aptr[k] : 0.f;
        Bs[lk + i][lrow] = (nok && k < K) ? bptr[k] : 0.f;
      }
    }
    __syncthreads();
#pragma unroll
    for (int kk = 0; kk < 32; kk++) {
      float4 a = *(const float4*)&As[kk][tm * 4];
      float4 b = *(const float4*)&Bs[kk][tn * 4];
      FMA16(a, b, acc)
    }
    __syncthreads();
  }
#pragma unroll
  for (int i = 0; i < 4; i++) {
    int m = m0 + tm * 4 + i;
    if (m >= M) continue;
#pragma unroll
    for (int j = 0; j < 4; j++) {
      int n = n0 + tn * 4 + j;
      if (n >= N) continue;
      float v = acc[i][j];
      if (HASBIAS) v += bias[n];
      C[(long)m * ldc + n] = v;
    }
  }
}

// ---------------- split-bf16 MFMA GEMM, pre-split A: C = A * B^T (+bias) ----
template <int AMODE, int BH, int HASBIAS>
__global__ __launch_bounds__(256) void mgemm_k(const unsigned short* __restrict__ AH,
                                               const unsigned short* __restrict__ AL,
                                               int lda, int at0,
                                               const float* __restrict__ B,
                                               const float* __restrict__ bias,
                                               float* __restrict__ C, int ldc, int K) {
  __shared__ __align__(16) unsigned short Ah[64 * 40], Al[64 * 40], Bh[64 * 40], Bl[64 * 40];
  int tid = threadIdx.x;
  int m0 = blockIdx.x * 64, n0 = blockIdx.y * 64;
  int srow = tid >> 2, skoff = (tid & 3) * 8;
  int am = m0 + srow;
  long arow = (AMODE == 1) ? ((long)(am & 31) * 256 + at0 + (am >> 5)) : (long)am;
  const unsigned short* aptrH = AH + arow * (long)lda;
  const unsigned short* aptrL = AL + arow * (long)lda;
  int bn = n0 + srow;
  long gsrc;
  if (BH > 0) gsrc = (long)(bn & 3) * BH + (bn >> 2);
  else gsrc = bn;
  const float* bptr = B + gsrc * (long)K;

  int lane = tid & 63, wv = tid >> 6;
  int wm = (wv >> 1) * 32, wn = (wv & 1) * 32;
  int fr = lane & 15, fk = (lane >> 4) * 8;
  int rbase = (lane >> 4) * 4;

  f32x4 acc[2][2] = {};
  for (int k0 = 0; k0 < K; k0 += 32) {
    int kb = k0 + skoff;
    uint4 vh, vl;
    unsigned short hb[8] __attribute__((aligned(16))), lb[8] __attribute__((aligned(16)));
    if (kb + 8 <= K) {
      vh = *(const uint4*)(aptrH + kb);
      vl = *(const uint4*)(aptrL + kb);
      float4 b0 = *(const float4*)(bptr + kb);
      float4 b1 = *(const float4*)(bptr + kb + 4);
      float bv[8] = {b0.x, b0.y, b0.z, b0.w, b1.x, b1.y, b1.z, b1.w};
#pragma unroll
      for (int e = 0; e < 8; e++) splitf(bv[e], hb[e], lb[e]);
    } else {
      unsigned short ea[8] __attribute__((aligned(16))), el[8] __attribute__((aligned(16)));
#pragma unroll
      for (int e = 0; e < 8; e++) {
        int k = kb + e;
        ea[e] = (k < K) ? aptrH[k] : 0;
        el[e] = (k < K) ? aptrL[k] : 0;
        float bvv = (k < K) ? bptr[k] : 0.f;
        splitf(bvv, hb[e], lb[e]);
      }
      vh = *(const uint4*)ea;
      vl = *(const uint4*)el;
    }
    __syncthreads();
    *(uint4*)&Ah[srow * 40 + skoff] = vh;
    *(uint4*)&Al[srow * 40 + skoff] = vl;
    *(uint4*)&Bh[srow * 40 + skoff] = *(const uint4*)hb;
    *(uint4*)&Bl[srow * 40 + skoff] = *(const uint4*)lb;
    __syncthreads();
    bf16x8 fah[2], fal[2], fbh[2], fbl[2];
#pragma unroll
    for (int i = 0; i < 2; i++) {
      fah[i] = *(const bf16x8*)&Ah[(wm + i * 16 + fr) * 40 + fk];
      fal[i] = *(const bf16x8*)&Al[(wm + i * 16 + fr) * 40 + fk];
      fbh[i] = *(const bf16x8*)&Bh[(wn + i * 16 + fr) * 40 + fk];
      fbl[i] = *(const bf16x8*)&Bl[(wn + i * 16 + fr) * 40 + fk];
    }
#pragma unroll
    for (int i = 0; i < 2; i++)
#pragma unroll
      for (int j = 0; j < 2; j++) {
        acc[i][j] = __builtin_amdgcn_mfma_f32_16x16x32_bf16(fah[i], fbh[j], acc[i][j], 0, 0, 0);
        acc[i][j] = __builtin_amdgcn_mfma_f32_16x16x32_bf16(fah[i], fbl[j], acc[i][j], 0, 0, 0);
        acc[i][j] = __builtin_amdgcn_mfma_f32_16x16x32_bf16(fal[i], fbh[j], acc[i][j], 0, 0, 0);
      }
  }
#pragma unroll
  for (int i = 0; i < 2; i++)
#pragma unroll
    for (int j = 0; j < 2; j++)
#pragma unroll
      for (int r = 0; r < 4; r++) {
        int m = m0 + wm + i * 16 + rbase + r;
        int n = n0 + wn + j * 16 + fr;
        float v = acc[i][j][r];
        if (HASBIAS) {
          long gs = (BH > 0) ? ((long)(n & 3) * BH + (n >> 2)) : (long)n;
          v += bias[gs];
        }
        C[(long)m * ldc + n] = v;
      }
}

// ---------------- MFMA GEMM, BOTH operands pre-split (qbuf) -----------------
// C[m][n] = A[m][:] . Bp[n][:], A rows plain, B rows plain, K%32==0, no bias.
__global__ __launch_bounds__(256) void mgemm2_k(const unsigned short* __restrict__ AH,
                                                const unsigned short* __restrict__ AL,
                                                int lda,
                                                const unsigned short* __restrict__ BHp,
                                                const unsigned short* __restrict__ BLp,
                                                float* __restrict__ C, int ldc, int K) {
  __shared__ __align__(16) unsigned short Ah[64 * 40], Al[64 * 40], Bh[64 * 40], Bl[64 * 40];
  int tid = threadIdx.x;
  int m0 = blockIdx.x * 64, n0 = blockIdx.y * 64;
  int srow = tid >> 2, skoff = (tid & 3) * 8;
  const unsigned short* aptrH = AH + (long)(m0 + srow) * lda;
  const unsigned short* aptrL = AL + (long)(m0 + srow) * lda;
  const unsigned short* bptrH = BHp + (long)(n0 + srow) * K;
  const unsigned short* bptrL = BLp + (long)(n0 + srow) * K;

  int lane = tid & 63, wv = tid >> 6;
  int wm = (wv >> 1) * 32, wn = (wv & 1) * 32;
  int fr = lane & 15, fk = (lane >> 4) * 8;
  int rbase = (lane >> 4) * 4;

  f32x4 acc[2][2] = {};
  for (int k0 = 0; k0 < K; k0 += 32) {
    int kb = k0 + skoff;
    uint4 vh = *(const uint4*)(aptrH + kb);
    uint4 vl = *(const uint4*)(aptrL + kb);
    uint4 bh4 = *(const uint4*)(bptrH + kb);
    uint4 bl4 = *(const uint4*)(bptrL + kb);
    __syncthreads();
    *(uint4*)&Ah[srow * 40 + skoff] = vh;
    *(uint4*)&Al[srow * 40 + skoff] = vl;
    *(uint4*)&Bh[srow * 40 + skoff] = bh4;
    *(uint4*)&Bl[srow * 40 + skoff] = bl4;
    __syncthreads();
    bf16x8 fah[2], fal[2], fbh[2], fbl[2];
#pragma unroll
    for (int i = 0; i < 2; i++) {
      fah[i] = *(const bf16x8*)&Ah[(wm + i * 16 + fr) * 40 + fk];
      fal[i] = *(const bf16x8*)&Al[(wm + i * 16 + fr) * 40 + fk];
      fbh[i] = *(const bf16x8*)&Bh[(wn + i * 16 + fr) * 40 + fk];
      fbl[i] = *(const bf16x8*)&Bl[(wn + i * 16 + fr) * 40 + fk];
    }
#pragma unroll
    for (int i = 0; i < 2; i++)
#pragma unroll
      for (int j = 0; j < 2; j++) {
        acc[i][j] = __builtin_amdgcn_mfma_f32_16x16x32_bf16(fah[i], fbh[j], acc[i][j], 0, 0, 0);
        acc[i][j] = __builtin_amdgcn_mfma_f32_16x16x32_bf16(fah[i], fbl[j], acc[i][j], 0, 0, 0);
        acc[i][j] = __builtin_amdgcn_mfma_f32_16x16x32_bf16(fal[i], fbh[j], acc[i][j], 0, 0, 0);
      }
  }
#pragma unroll
  for (int i = 0; i < 2; i++)
#pragma unroll
    for (int j = 0; j < 2; j++)
#pragma unroll
      for (int r = 0; r < 4; r++) {
        int m = m0 + wm + i * 16 + rbase + r;
        int n = n0 + wn + j * 16 + fr;
        C[(long)m * ldc + n] = acc[i][j][r];
      }
}

// ---------------- char-encoder fused step (ALL operands pre-split) ----------
// R8: Wx/Wh arrive as bf16 H/L pair arrays (same linear layout as the fp32
// originals) -> K-loop staging is pure uint4 loads, zero splitf VALU work.
template <int K1>
__global__ __launch_bounds__(256) void mstep_k(
    const unsigned short* __restrict__ xFH, const unsigned short* __restrict__ xFL,
    const unsigned short* __restrict__ xBH, const unsigned short* __restrict__ xBL,
    int xstride,
    const unsigned short* __restrict__ WxH, const unsigned short* __restrict__ WxL,
    const unsigned short* __restrict__ WhH, const unsigned short* __restrict__ WhL,
    const float* __restrict__ bias,
    const unsigned short* __restrict__ hInH, const unsigned short* __restrict__ hInL,
    unsigned short* __restrict__ hOutH, unsigned short* __restrict__ hOutL,
    float* __restrict__ c_st,
    unsigned short* __restrict__ outH, unsigned short* __restrict__ outL,
    int out_stride, int tF, int tB) {
  __shared__ __align__(16) char smem[20480];
  unsigned short* Ah = (unsigned short*)smem;
  unsigned short* Al = Ah + 2560;
  unsigned short* Bh = Ah + 5120;
  unsigned short* Bl = Ah + 7680;
  float* gbuf = (float*)smem;  // [64][68] after MFMA loop (17408 B)

  int tid = threadIdx.x;
  int m0 = blockIdx.x * 64, n0 = blockIdx.y * 64;
  int dir = n0 >> 11;
  int nn0 = n0 & 2047;
  int srow = tid >> 2, skoff = (tid & 3) * 8;

  int am = m0 + srow;
  const unsigned short* axH = dir ? xBH : xFH;
  const unsigned short* axL = dir ? xBL : xFL;
  const unsigned short* arow_xH = axH + (long)am * xstride;
  const unsigned short* arow_xL = axL + (long)am * xstride;
  const unsigned short* arow_hH = hInH + (long)dir * 262144 + (long)am * 512;
  const unsigned short* arow_hL = hInL + (long)dir * 262144 + (long)am * 512;

  int bn = nn0 + srow;
  long gsrc = (long)dir * 2048 + (bn & 3) * 512 + (bn >> 2);
  const unsigned short* brow_xH = WxH + gsrc * (long)K1;
  const unsigned short* brow_xL = WxL + gsrc * (long)K1;
  const unsigned short* brow_hH = WhH + gsrc * 512L;
  const unsigned short* brow_hL = WhL + gsrc * 512L;

  int lane = tid & 63, wv = tid >> 6;
  int wm = (wv >> 1) * 32, wn = (wv & 1) * 32;
  int fr = lane & 15, fk = (lane >> 4) * 8;
  int rbase = (lane >> 4) * 4;

  f32x4 acc[2][2] = {};
  const int K = K1 + 512;
  for (int k0 = 0; k0 < K; k0 += 32) {
    int kb = k0 + skoff;
    uint4 vh, vl, bh4, bl4;
    if (kb < K1) {
      vh = *(const uint4*)(arow_xH + kb);
      vl = *(const uint4*)(arow_xL + kb);
      bh4 = *(const uint4*)(brow_xH + kb);
      bl4 = *(const uint4*)(brow_xL + kb);
    } else {
      vh = *(const uint4*)(arow_hH + (kb - K1));
      vl = *(const uint4*)(arow_hL + (kb - K1));
      bh4 = *(const uint4*)(brow_hH + (kb - K1));
      bl4 = *(const uint4*)(brow_hL + (kb - K1));
    }
    __syncthreads();
    *(uint4*)&Ah[srow * 40 + skoff] = vh;
    *(uint4*)&Al[srow * 40 + skoff] = vl;
    *(uint4*)&Bh[srow * 40 + skoff] = bh4;
    *(uint4*)&Bl[srow * 40 + skoff] = bl4;
    __syncthreads();
    bf16x8 fah[2], fal[2], fbh[2], fbl[2];
#pragma unroll
    for (int i = 0; i < 2; i++) {
      fah[i] = *(const bf16x8*)&Ah[(wm + i * 16 + fr) * 40 + fk];
      fal[i] = *(const bf16x8*)&Al[(wm + i * 16 + fr) * 40 + fk];
      fbh[i] = *(const bf16x8*)&Bh[(wn + i * 16 + fr) * 40 + fk];
      fbl[i] = *(const bf16x8*)&Bl[(wn + i * 16 + fr) * 40 + fk];
    }
#pragma unroll
    for (int i = 0; i < 2; i++)
#pragma unroll
      for (int j = 0; j < 2; j++) {
        acc[i][j] = __builtin_amdgcn_mfma_f32_16x16x32_bf16(fah[i], fbh[j], acc[i][j], 0, 0, 0);
        acc[i][j] = __builtin_amdgcn_mfma_f32_16x16x32_bf16(fah[i], fbl[j], acc[i][j], 0, 0, 0);
        acc[i][j] = __builtin_amdgcn_mfma_f32_16x16x32_bf16(fal[i], fbh[j], acc[i][j], 0, 0, 0);
      }
  }
  __syncthreads();  // tiles dead; reuse LDS as gate buffer
#pragma unroll
  for (int i = 0; i < 2; i++)
#pragma unroll
    for (int j = 0; j < 2; j++)
#pragma unroll
      for (int r = 0; r < 4; r++)
        gbuf[(wm + i * 16 + rbase + r) * 68 + (wn + j * 16 + fr)] = acc[i][j][r];
  __syncthreads();

  int ug0 = nn0 >> 2;
  int t = dir ? tB : tF;
  for (int it = tid; it < 1024; it += 256) {
    int r = it >> 4, ul = it & 15;
    int seq = m0 + r, ug = ug0 + ul;
    float gi = gbuf[r * 68 + ul * 4 + 0] + bias[dir * 2048 + ug];
    float gf = gbuf[r * 68 + ul * 4 + 1] + bias[dir * 2048 + 512 + ug];
    float gg = gbuf[r * 68 + ul * 4 + 2] + bias[dir * 2048 + 1024 + ug];
    float go = gbuf[r * 68 + ul * 4 + 3] + bias[dir * 2048 + 1536 + ug];
    long ci = (long)dir * 262144 + (long)seq * 512 + ug;
    float c = sigf(gf) * c_st[ci] + sigf(gi) * tanhf(gg);
    float h = sigf(go) * tanhf(c);
    c_st[ci] = c;
    unsigned short hh, hl;
    splitf(h, hh, hl);
    hOutH[ci] = hh;
    hOutL[ci] = hl;
    long oo = ((long)seq * 16 + t) * out_stride + dir * 512 + ug;
    outH[oo] = hh;
    outL[oo] = hl;
  }
}

// ---------------- sentence recurrent ----------------
__global__ __launch_bounds__(256) void sent_rec_k(const float* __restrict__ pre,
                                                  const float* __restrict__ WhT,
                                                  float* __restrict__ out) {
  int blk = blockIdx.x;
  int n = blk & 31, dir = blk >> 5;
  int tid = threadIdx.x;
  __shared__ float hls[256];
  __shared__ float gls[1024];
  float c = 0.f;
  hls[tid] = 0.f;
  __syncthreads();
  const float* whbase = WhT + (long)dir * 256 * 1024;
  int g4 = tid * 4;
  for (int s = 0; s < 16; s++) {
    int t = dir ? (15 - s) : s;
    const float* prow = pre + (long)(n * 16 + t) * 2048 + dir * 1024;
    float ax = 0.f, ay = 0.f, az = 0.f, aw = 0.f;
#pragma unroll 4
    for (int k = 0; k < 256; k++) {
      float hk = hls[k];
      float4 w = *(const float4*)(whbase + (long)k * 1024 + g4);
      ax += hk * w.x; ay += hk * w.y; az += hk * w.z; aw += hk * w.w;
    }
    float4 p = *(const float4*)(prow + g4);
    gls[g4 + 0] = ax + p.x; gls[g4 + 1] = ay + p.y;
    gls[g4 + 2] = az + p.z; gls[g4 + 3] = aw + p.w;
    __syncthreads();
    float gi = gls[tid], gf = gls[256 + tid], gg = gls[512 + tid], go = gls[768 + tid];
    c = sigf(gf) * c + sigf(gi) * tanhf(gg);
    float h = sigf(go) * tanhf(c);
    __syncthreads();
    hls[tid] = h;
    out[(long)n * 8192 + (long)t * 512 + dir * 256 + tid] = h;
    __syncthreads();
  }
}

// load one K-step of A(H/L) + B(split to hb/lb) into registers
#define GLOADK(k0v)                                                         \
  {                                                                         \
    int kb = (k0v) + skoff;                                                 \
    if (kb + 8 <= 1544) {                                                   \
      vh = *(const uint4*)(aptrH + kb);                                     \
      vl = *(const uint4*)(aptrL + kb);                                     \
      float4 b0 = *(const float4*)(bptr + kb);                              \
      float4 b1 = *(const float4*)(bptr + kb + 4);                          \
      float bv[8] = {b0.x, b0.y, b0.z, b0.w, b1.x, b1.y, b1.z, b1.w};       \
      _Pragma("unroll") for (int e = 0; e < 8; e++)                         \
          splitf(bv[e], hb[e], lb[e]);                                      \
    } else {                                                                \
      unsigned short ea[8] __attribute__((aligned(16)));                    \
      unsigned short el[8] __attribute__((aligned(16)));                    \
      _Pragma("unroll") for (int e = 0; e < 8; e++) {                       \
        int k = kb + e;                                                     \
        ea[e] = (k < 1544) ? aptrH[k] : 0;                                  \
        el[e] = (k < 1544) ? aptrL[k] : 0;                                  \
        float bvv = (k < 1544) ? bptr[k] : 0.f;                             \
        splitf(bvv, hb[e], lb[e]);                                          \
      }                                                                     \
      vh = *(const uint4*)ea;                                               \
      vl = *(const uint4*)el;                                               \
    }                                                                       \
  }

#define WLDS(bufp)                                                          \
  {                                                                         \
    unsigned short* W_ = (bufp);                                            \
    *(uint4*)&W_[srow * 40 + skoff] = vh;                                   \
    *(uint4*)&W_[2560 + srow * 40 + skoff] = vl;                            \
    *(uint4*)&W_[5120 + srow * 40 + skoff] = *(const uint4*)hb;             \
    *(uint4*)&W_[7680 + srow * 40 + skoff] = *(const uint4*)lb;             \
  }

// ---------------- fused decoder + next-chunk Wx GEMM (unchanged from R7) ----
__global__ __launch_bounds__(256, 1) void dec_fused_k(
    const unsigned short* __restrict__ WhFH, const unsigned short* __restrict__ WhFL,
    const float* __restrict__ pre,
    unsigned short* __restrict__ hH, unsigned short* __restrict__ hL,
    float* __restrict__ c_st, float* __restrict__ dec_out,
    int* __restrict__ cnt, int tbase,
    const unsigned short* __restrict__ AH, const unsigned short* __restrict__ AL,
    const float* __restrict__ Bw, const float* __restrict__ bias,
    float* __restrict__ pre_nxt, int at0, int do_gemm) {
  extern __shared__ char smem[];
  int tid = threadIdx.x, bid = blockIdx.x;

  if (bid < 128) {
    // ======================= decoder (R3 config) =======================
    unsigned short* wHs = (unsigned short*)smem;            // 64 KB
    unsigned short* wLs = (unsigned short*)(smem + 65536);  // 64 KB
    float* gbuf = (float*)(smem + 131072);                  // [4][32][33]

    int lane = tid & 63, kh = tid >> 6;
    int fr = lane & 15, fq = (lane >> 4) & 3;
    int grp = bid >> 3;  // 16 groups of 8 blocks

    {
      const unsigned short* gH = WhFH + (long)bid * 32768;
      const unsigned short* gL = WhFL + (long)bid * 32768;
      for (int o = tid * 8; o < 32768; o += 2048) {
        *(uint4*)&wHs[o] = *(const uint4*)&gH[o];
        *(uint4*)&wLs[o] = *(const uint4*)&gL[o];
      }
    }

    int bb = tid >> 2, up = tid & 3;
    int u0 = bid * 8 + up * 2;
    long co = (long)bb * 1024 + u0;
    float c0 = 0.f, c1 = 0.f;
    if (tid < 128) {
      float2 cc = *(const float2*)&c_st[co];
      c0 = cc.x;
      c1 = cc.y;
    }
    __syncthreads();

    for (int tl = 0; tl < 32; tl++) {
      int t = tbase + tl;
      const unsigned short* hInH = hH + (long)(t & 1) * 32768;
      const unsigned short* hInL = hL + (long)(t & 1) * 32768;
      unsigned short* hOutH = hH + (long)((t + 1) & 1) * 32768;
      unsigned short* hOutL = hL + (long)((t + 1) & 1) * 32768;

      float4 p0 = {0.f, 0.f, 0.f, 0.f}, p1 = {0.f, 0.f, 0.f, 0.f};
      if (tid < 128) {
        const float* pr = pre + ((long)tl * 32 + bb) * 4096 + bid * 32 + up * 8;
        p0 = *(const float4*)pr;
        p1 = *(const float4*)(pr + 4);
      }

      // all 32 h-fragment loads in flight, one waitcnt (batched sc1 loads)
      u32x4 hHr[2][8], hLr[2][8];
#pragma unroll
      for (int bh = 0; bh < 2; bh++)
#pragma unroll
        for (int i = 0; i < 8; i++) {
          long a = (long)(bh * 16 + fr) * 1024 + (kh * 8 + i) * 32 + fq * 8;
          ldg16_cc(hHr[bh][i], hInH + a);
          ldg16_cc(hLr[bh][i], hInL + a);
        }
      asm volatile("s_waitcnt vmcnt(0)");
      __builtin_amdgcn_sched_barrier(0);

      f32x4 acc[2][2] = {};  // [col-tile ct][batch-half bh]
#pragma unroll
      for (int i = 0; i < 8; i++) {
        int kt = kh * 8 + i;
#pragma unroll
        for (int ct = 0; ct < 2; ct++) {
          bf16x8 wh = *(const bf16x8*)&wHs[(ct * 32 + kt) * 512 + lane * 8];
          bf16x8 wl = *(const bf16x8*)&wLs[(ct * 32 + kt) * 512 + lane * 8];
#pragma unroll
          for (int bh = 0; bh < 2; bh++) {
            bf16x8 ah = __builtin_bit_cast(bf16x8, hHr[bh][i]);
            bf16x8 al = __builtin_bit_cast(bf16x8, hLr[bh][i]);
            acc[ct][bh] = __builtin_amdgcn_mfma_f32_16x16x32_bf16(ah, wh, acc[ct][bh], 0, 0, 0);
            acc[ct][bh] = __builtin_amdgcn_mfma_f32_16x16x32_bf16(ah, wl, acc[ct][bh], 0, 0, 0);
            acc[ct][bh] = __builtin_amdgcn_mfma_f32_16x16x32_bf16(al, wh, acc[ct][bh], 0, 0, 0);
          }
        }
      }
#pragma unroll
      for (int ct = 0; ct < 2; ct++)
#pragma unroll
        for (int bh = 0; bh < 2; bh++)
#pragma unroll
          for (int r = 0; r < 4; r++)
            gbuf[(kh * 32 + bh * 16 + fq * 4 + r) * 33 + ct * 16 + fr] = acc[ct][bh][r];
      __syncthreads();

      if (tid < 128) {
        float g[8];
#pragma unroll
        for (int e = 0; e < 8; e++) {
          float s = gbuf[bb * 33 + up * 8 + e];
#pragma unroll
          for (int q = 1; q < 4; q++) s += gbuf[(q * 32 + bb) * 33 + up * 8 + e];
          g[e] = s;
        }
        c0 = sigf(g[1] + p0.y) * c0 + sigf(g[0] + p0.x) * tanhf(g[2] + p0.z);
        float h0 = sigf(g[3] + p0.w) * tanhf(c0);
        c1 = sigf(g[5] + p1.y) * c1 + sigf(g[4] + p1.x) * tanhf(g[6] + p1.z);
        float h1 = sigf(g[7] + p1.w) * tanhf(c1);
        unsigned short h0h, h0l, h1h, h1l;
        splitf(h0, h0h, h0l);
        splitf(h1, h1h, h1l);
        unsigned ph = (unsigned)h0h | ((unsigned)h1h << 16);
        unsigned pl = (unsigned)h0l | ((unsigned)h1l << 16);
        __hip_atomic_store((unsigned*)(hOutH + co), ph, __ATOMIC_RELAXED,
                           __HIP_MEMORY_SCOPE_AGENT);
        __hip_atomic_store((unsigned*)(hOutL + co), pl, __ATOMIC_RELAXED,
                           __HIP_MEMORY_SCOPE_AGENT);
        float2 hv;
        hv.x = h0;
        hv.y = h1;
        *(float2*)&dec_out[((long)bb * 256 + t) * 1024 + u0] = hv;
      }
      __syncthreads();  // drains vmcnt -> all h stores at LLC

      // barrier every step; absolute-step targets (cnt monotonic over chunks)
      if (tid == 0) {
        int old = __hip_atomic_fetch_add(&cnt[grp * 32], 1, __ATOMIC_RELAXED,
                                         __HIP_MEMORY_SCOPE_AGENT);
        if (old == 8 * t + 7)
          __hip_atomic_fetch_add(&cnt[512], 1, __ATOMIC_RELAXED,
                                 __HIP_MEMORY_SCOPE_AGENT);
        while (__hip_atomic_load(&cnt[512], __ATOMIC_RELAXED,
                                 __HIP_MEMORY_SCOPE_AGENT) < 16 * (t + 1))
          __builtin_amdgcn_s_sleep(1);
      }
      __syncthreads();
    }
    if (tid < 128) {
      float2 cv;
      cv.x = c0;
      cv.y = c1;
      *(float2*)&c_st[co] = cv;
    }
  } else if (do_gemm) {
    // ====== next-chunk dec_Wx GEMM: double-buffered, 1 barrier/K-step ======
    unsigned short* lbase = (unsigned short*)smem;
    const int K = 1544;
    int srow = tid >> 2, skoff = (tid & 3) * 8;
    int lane = tid & 63, wv = tid >> 6;
    int wm = (wv >> 1) * 32, wn = (wv & 1) * 32;
    int fr = lane & 15, fk = (lane >> 4) * 8;
    int rbase = (lane >> 4) * 4;
    int gid = bid - 128;

    for (int t8 = 0; t8 < 8; t8++) {
      int tile = gid + 128 * t8;
      int m0 = (tile & 15) * 64, n0 = (tile >> 4) * 64;
      int am = m0 + srow;
      long arow = (long)(am & 31) * 256 + at0 + (am >> 5);
      const unsigned short* aptrH = AH + arow * 1544L;
      const unsigned short* aptrL = AL + arow * 1544L;
      int bn = n0 + srow;
      long gsrc = (long)(bn & 3) * 1024 + (bn >> 2);
      const float* bptr = Bw + gsrc * 1544L;

      f32x4 acc[2][2] = {};
      uint4 vh, vl;
      unsigned short hb[8] __attribute__((aligned(16)));
      unsigned short lb[8] __attribute__((aligned(16)));

      GLOADK(0);
      __syncthreads();
      WLDS(lbase);
      int cur = 0;

      for (int k0 = 0; k0 < K; k0 += 32) {
        __syncthreads();
        bool more = (k0 + 32 < K);
        if (more) GLOADK(k0 + 32);
        unsigned short* Bf = lbase + cur * 10240;
        bf16x8 fah[2], fal[2], fbh[2], fbl[2];
#pragma unroll
        for (int i = 0; i < 2; i++) {
          fah[i] = *(const bf16x8*)&Bf[(wm + i * 16 + fr) * 40 + fk];
          fal[i] = *(const bf16x8*)&Bf[2560 + (wm + i * 16 + fr) * 40 + fk];
          fbh[i] = *(const bf16x8*)&Bf[5120 + (wn + i * 16 + fr) * 40 + fk];
          fbl[i] = *(const bf16x8*)&Bf[7680 + (wn + i * 16 + fr) * 40 + fk];
        }
#pragma unroll
        for (int i = 0; i < 2; i++)
#pragma unroll
          for (int j = 0; j < 2; j++) {
            acc[i][j] = __builtin_amdgcn_mfma_f32_16x16x32_bf16(fah[i], fbh[j], acc[i][j], 0, 0, 0);
            acc[i][j] = __builtin_amdgcn_mfma_f32_16x16x32_bf16(fah[i], fbl[j], acc[i][j], 0, 0, 0);
            acc[i][j] = __builtin_amdgcn_mfma_f32_16x16x32_bf16(fal[i], fbh[j], acc[i][j], 0, 0, 0);
          }
        if (more) {
          WLDS(lbase + (cur ^ 1) * 10240);
          cur ^= 1;
        }
      }
#pragma unroll
      for (int i = 0; i < 2; i++)
#pragma unroll
        for (int j = 0; j < 2; j++)
#pragma unroll
          for (int r = 0; r < 4; r++) {
            int m = m0 + wm + i * 16 + rbase + r;
            int n = n0 + wn + j * 16 + fr;
            long gs = (long)(n & 3) * 1024 + (n >> 2);
            pre_nxt[(long)m * 4096 + n] = acc[i][j][r] + bias[gs];
          }
    }
  }
}

// ---------------- attention ----------------
__global__ __launch_bounds__(256) void attn_k(const float* __restrict__ sent_enc,
                                              const float* __restrict__ qbuf,
                                              const int* __restrict__ words,
                                              float* __restrict__ attn_out,
                                              unsigned short* __restrict__ fH,
                                              unsigned short* __restrict__ fL) {
  int b = blockIdx.x >> 4;
  int i = blockIdx.x & 15;
  int tid = threadIdx.x;
  __shared__ float se[16][512];
  __shared__ float qq[16][512];
  __shared__ float sc[16][16];
  __shared__ int kv[16];
  if (tid < 16) kv[tid] = 0;
  __syncthreads();
  {
    int j = tid >> 4, c = tid & 15;
    if (words[(b * 16 + j) * 16 + c] != 0) atomicOr(&kv[j], 1);
  }
  for (int idx = tid; idx < 16 * 128; idx += 256) {
    int j = idx >> 7, d4 = idx & 127;
    *(float4*)&se[j][d4 * 4] = *(const float4*)(sent_enc + (long)(b * 16 + j) * 512 + d4 * 4);
  }
  for (int idx = tid; idx < 16 * 128; idx += 256) {
    int c = idx >> 7, d4 = idx & 127;
    *(float4*)&qq[c][d4 * 4] = *(const float4*)(qbuf + (long)(b * 256 + i * 16 + c) * 512 + d4 * 4);
  }
  __syncthreads();
  int c = tid >> 4, j = tid & 15;
  {
    float s = 0.f;
#pragma unroll 4
    for (int k = 0; k < 512; k++) s += qq[c][k] * se[j][k];
    bool valid = (kv[j] != 0) && (j != i);
    sc[c][j] = valid ? s : -1e9f;
  }
  __syncthreads();
  float m = -INFINITY;
#pragma unroll
  for (int t = 0; t < 16; t++) m = fmaxf(m, sc[c][t]);
  float den = 0.f;
#pragma unroll
  for (int t = 0; t < 16; t++) den += expf(sc[c][t] - m);
  float a = expf(sc[c][j] - m) / den;
  __syncthreads();
  sc[c][j] = a;
  attn_out[((long)((b * 16 + i) * 16 + c)) * 16 + j] = a;
  __syncthreads();
  {
    int part = tid & 15;
    int cc = tid >> 4;
    for (int d = part * 32; d < part * 32 + 32; d++) {
      float v = 0.f;
#pragma unroll
      for (int jj = 0; jj < 16; jj++) v += sc[cc][jj] * se[jj][d];
      long o = (long)(b * 256 + i * 16 + cc) * 1544 + d;
      unsigned short hh, hl;
      splitf(v, hh, hl);
      fH[o] = hh;
      fL[o] = hl;
    }
  }
}

// ---------------------------------------------------------------------------
extern "C" void kernel_launch(void* const* d_in, const int* in_sizes, int n_in,
                              void* d_out, int out_size, void* d_ws, size_t ws_size,
                              hipStream_t stream) {
  const int* sents = (const int*)d_in[0];
  const int* words = (const int*)d_in[1];
  const int* labels = (const int*)d_in[2];
  const float* word_embs = (const float*)d_in[3];
  const float* char_table = (const float*)d_in[4];
  const float* sent_Wx0 = (const float*)d_in[5];
  const float* sent_Wh0 = (const float*)d_in[6];
  const float* sent_b0 = (const float*)d_in[7];
  const float* sent_Wx1 = (const float*)d_in[8];
  const float* sent_Wh1 = (const float*)d_in[9];
  const float* sent_b1 = (const float*)d_in[10];
  const float* word_Wx0 = (const float*)d_in[11];
  const float* word_Wh0 = (const float*)d_in[12];
  const float* word_b0 = (const float*)d_in[13];
  const float* word_Wx1 = (const float*)d_in[14];
  const float* word_Wh1 = (const float*)d_in[15];
  const float* word_b1 = (const float*)d_in[16];
  const float* attn_Wq = (const float*)d_in[17];
  const float* dec_Wx = (const float*)d_in[18];
  const float* dec_Wh = (const float*)d_in[19];
  const float* dec_b = (const float*)d_in[20];
  const float* cls_W = (const float*)d_in[21];
  const float* cls_b = (const float*)d_in[22];

  char* base = (char*)d_ws;
  // ---- Slot Z (early phase; overlaid by WhF pairs during decoder) ---------
  float* wembs   = (float*)(base + 0);          // 153600 fl
  float* preS    = (float*)(base + 614400);     // 1048576 fl
  float* hs0     = (float*)(base + 4808704);    // 262144 fl
  float* WhT0    = (float*)(base + 5857280);    // 524288 fl
  float* WhT1    = (float*)(base + 7954432);    // 524288 fl
  float* sentenc = (float*)(base + 10051584);   // 262144 fl
  unsigned short* hcharH = (unsigned short*)(base + 11100160);  // 1048576 us
  unsigned short* hcharL = (unsigned short*)(base + 13197312);  // 1048576 us
  float* cchar   = (float*)(base + 15294464);   // 524288 fl  (Z ends 17391616)
  unsigned short* WhFH = (unsigned short*)(base + 0);        // 4194304 us (overlay)
  unsigned short* WhFL = (unsigned short*)(base + 8388608);  // 4194304 us
  // word-Wh0 pairs overlay dead sentence-encoder space (after sent_rec #2,
  // dead before decwh_prep overlays): base+0..8388608
  unsigned short* Wh0H = (unsigned short*)(base + 0);          // 2097152 us
  unsigned short* Wh0L = (unsigned short*)(base + 4194304);    // 2097152 us
  // WqT pairs overlay cchar (dead after char layer1, used by qbuf GEMM,
  // clobbered later by decwh WhFL -- which runs after): 15294464..17391616
  unsigned short* WqTpH = (unsigned short*)(base + 15294464);  // 524288 us
  unsigned short* WqTpL = (unsigned short*)(base + 16343040);  // 524288 us
  // ---- Slot W: finalb pairs ----------------------------------------------
  unsigned short* finalbH = (unsigned short*)(base + 17391616);  // 12648448 us
  unsigned short* finalbL = (unsigned short*)(base + 42688512);  // 12648448 us
  // ---- Slot Y: Wx0 pairs (layer0) / Wh1 pairs (layer1) / q / pre ----------
  float* qbuf = (float*)(base + 67985408);
  float* pre0 = qbuf;
  unsigned short* Wx0H = (unsigned short*)(base + 67985408);   // 2228224 us
  unsigned short* Wx0L = (unsigned short*)(base + 72441856);   // 2228224 us
  unsigned short* Wh1H = (unsigned short*)(base + 67985408);   // 2097152 us (after layer0)
  unsigned short* Wh1L = (unsigned short*)(base + 72179712);   // 2097152 us
  // ---- WqT ----------------------------------------------------------------
  float* WqT = (float*)(base + 84762624);       // 524288 fl
  // ---- Slot X (char phase; overlaid by decoder/classifier buffers) --------
  unsigned short* charinH = (unsigned short*)(base + 86859776);   // 4456448 us
  unsigned short* charinL = (unsigned short*)(base + 95772672);   // 4456448 us
  unsigned short* Wx1H = (unsigned short*)(base + 86859776);      // 4194304 us (after layer0)
  unsigned short* Wx1L = (unsigned short*)(base + 95248384);      // 4194304 us
  unsigned short* hc0H = (unsigned short*)(base + 104685568);     // 8388608 us
  unsigned short* hc0L = (unsigned short*)(base + 121462784);     // 8388608 us (X ends 138240000)
  float* dec_out = (float*)(base + 86859776);                     // 8388608 fl (overlay)
  unsigned short* hdecH = (unsigned short*)(base + 120414208);    // 65536 us
  unsigned short* hdecL = (unsigned short*)(base + 120545280);    // 65536 us
  float* c_dec = (float*)(base + 120676352);                      // 32768 fl
  float* clsWT = (float*)(base + 120807424);                      // 15360 fl
  int* cnt = (int*)(base + 120868864);                            // 1024 int (barrier)
  float* pre1 = (float*)(base + 121462784);                       // 4194304 fl (overlays dead hc0L)

  float* dout = (float*)d_out;
  float* diac = dout;              // 8192 x 15
  float* attnmap = dout + 122880;  // 32 x 16 x 16 x 16

  // one-time: allow 144.5 KB dynamic LDS on the fused decoder
  static bool s_dec_attr = false;
  if (!s_dec_attr) {
    hipFuncSetAttribute(reinterpret_cast<const void*>(dec_fused_k),
                        hipFuncAttributeMaxDynamicSharedMemorySize, 147968);
    s_dec_attr = true;
  }

  // ---- weight preprocessing (sentence + attention) --------------------------
  transpose_k<<<dim3(32, 8), 256, 0, stream>>>(sent_Wh0, WhT0, 1024, 256, 0);
  transpose_k<<<dim3(32, 8), 256, 0, stream>>>(sent_Wh0 + 262144, WhT0 + 262144, 1024, 256, 0);
  transpose_k<<<dim3(32, 8), 256, 0, stream>>>(sent_Wh1, WhT1, 1024, 256, 0);
  transpose_k<<<dim3(32, 8), 256, 0, stream>>>(sent_Wh1 + 262144, WhT1 + 262144, 1024, 256, 0);
  transpose_k<<<dim3(32, 16), 256, 0, stream>>>(attn_Wq, WqT, 1024, 512, 0);

  // ---- sentence encoder -----------------------------------------------------
  embed_k<<<600, 256, 0, stream>>>(sents, word_embs, wembs);
  gemm_k<1><<<dim3(8, 32), 256, 0, stream>>>(wembs, 300, sent_Wx0, sent_b0,
                                             preS, 2048, 512, 2048, 300);
  sent_rec_k<<<64, 256, 0, stream>>>(preS, WhT0, hs0);
  gemm_k<1><<<dim3(8, 32), 256, 0, stream>>>(hs0, 512, sent_Wx1, sent_b1,
                                             preS, 2048, 512, 2048, 512);
  sent_rec_k<<<64, 256, 0, stream>>>(preS, WhT1, sentenc);

  // ---- char encoder ---------------------------------------------------------
  charin_k<<<17408, 256, 0, stream>>>(words, char_table, sentenc, charinH, charinL);
  // pre-split layer0 weights (sentence-encoder scratch now dead)
  wprep_k<<<8192, 256, 0, stream>>>(word_Wh0, Wh0H, Wh0L, 2097152);
  wprep_k<<<8704, 256, 0, stream>>>(word_Wx0, Wx0H, Wx0L, 2228224);

  hipMemsetAsync(base + 11100160, 0, 6291456, stream);  // hcharH/L + cchar
  for (int s = 0; s < 16; s++) {
    int p = s & 1;
    mstep_k<544><<<dim3(8, 64), 256, 0, stream>>>(
        charinH + s * 544, charinL + s * 544,
        charinH + (15 - s) * 544, charinL + (15 - s) * 544, 16 * 544,
        Wx0H, Wx0L, Wh0H, Wh0L, word_b0,
        hcharH + p * 524288, hcharL + p * 524288,
        hcharH + (p ^ 1) * 524288, hcharL + (p ^ 1) * 524288, cchar,
        hc0H, hc0L, 1024, s, 15 - s);
  }
  // pre-split layer1 weights (charin + Wx0 regions now dead)
  wprep_k<<<16384, 256, 0, stream>>>(word_Wx1, Wx1H, Wx1L, 4194304);
  wprep_k<<<8192, 256, 0, stream>>>(word_Wh1, Wh1H, Wh1L, 2097152);
  hipMemsetAsync(base + 11100160, 0, 6291456, stream);
  for (int s = 0; s < 16; s++) {
    int p = s & 1;
    mstep_k<1024><<<dim3(8, 64), 256, 0, stream>>>(
        hc0H + s * 1024, hc0L + s * 1024,
        hc0H + (15 - s) * 1024, hc0L + (15 - s) * 1024, 16 * 1024,
        Wx1H, Wx1L, Wh1H, Wh1L, word_b1,
        hcharH + p * 524288, hcharL + p * 524288,
        hcharH + (p ^ 1) * 524288, hcharL + (p ^ 1) * 524288, cchar,
        finalbH + 512, finalbL + 512, 1544, s, 15 - s);
  }

  // ---- attention ------------------------------------------------------------
  wprep_k<<<2048, 256, 0, stream>>>(WqT, WqTpH, WqTpL, 524288);  // cchar dead
  mgemm2_k<<<dim3(128, 8), 256, 0, stream>>>(finalbH + 512, finalbL + 512, 1544,
                                             WqTpH, WqTpL, qbuf, 512, 1024);
  attn_k<<<512, 256, 0, stream>>>(sentenc, qbuf, words, attnmap, finalbH, finalbL);
  labels_k<<<256, 256, 0, stream>>>(labels, finalbH, finalbL);

  // ---- decoder: chunk0 pre, then 8 fused (decoder ch ∥ GEMM ch+1) ----------
  decwh_prep_k<<<16384, 256, 0, stream>>>(dec_Wh, WhFH, WhFL);  // overlays Slot Z
  hipMemsetAsync(base + 120414208, 0, 393216, stream);          // hdecH/L + c_dec
  hipMemsetAsync(cnt, 0, 4096, stream);                         // barrier counters (once)
  mgemm_k<1, 1024, 1><<<dim3(16, 64), 256, 0, stream>>>(finalbH, finalbL, 1544, 0,
                                                        dec_Wx, dec_b, pre0, 4096, 1544);
  float* preBuf[2] = {pre0, pre1};
  for (int ch = 0; ch < 8; ch++) {
    dec_fused_k<<<256, 256, 147968, stream>>>(
        WhFH, WhFL, preBuf[ch & 1], hdecH, hdecL, c_dec, dec_out, cnt, ch * 32,
        finalbH, finalbL, dec_Wx, dec_b, preBuf[(ch + 1) & 1], (ch + 1) * 32,
        (ch < 7) ? 1 : 0);
  }

  // ---- classifier -----------------------------------------------------------
  transpose_k<<<dim3(32, 1), 256, 0, stream>>>(cls_W, clsWT, 1024, 15, 0);
  gemm_k<1><<<dim3(128, 1), 256, 0, stream>>>(dec_out, 1024, clsWT, cls_b,
                                              diac, 15, 8192, 15, 1024);
}